// Round 5
// baseline (18299.521 us; speedup 1.0000x reference)
//
#include <hip/hip_runtime.h>
#include <hip/hip_cooperative_groups.h>
#include <cfloat>
#include <cmath>

#define N_Q 4096
#define N_S 1600
#define DIM 1024
#define N_C 64
#define KNN 12
#define MAX_ITER 50
#define EPS_CONV 1e-4f
#define NBLK 256         // tail_loop grid size
#define ADJ_CAP 96       // per-row LDS adjacency capacity (multiple of 8)
#define CHK 256          // P0a: Pt features staged per LDS chunk

typedef _Float16 h8 __attribute__((ext_vector_type(8)));
typedef float    f4 __attribute__((ext_vector_type(4)));

__device__ __forceinline__ float wave_max64(float v){
  #pragma unroll
  for (int o = 32; o; o >>= 1) v = fmaxf(v, __shfl_xor(v, o, 64));
  return v;
}
__device__ __forceinline__ float wave_sum64(float v){
  #pragma unroll
  for (int o = 32; o; o >>= 1) v += __shfl_xor(v, o, 64);
  return v;
}
__device__ __forceinline__ float wave_min64(float v){
  #pragma unroll
  for (int o = 32; o; o >>= 1) v = fminf(v, __shfl_xor(v, o, 64));
  return v;
}

// coherent (device-visible) element accesses for cross-block-communicated data
__device__ __forceinline__ float aload(const float* p){
  return __hip_atomic_load(p, __ATOMIC_RELAXED, __HIP_MEMORY_SCOPE_AGENT);
}
__device__ __forceinline__ void astore(float* p, float v){
  __hip_atomic_store(p, v, __ATOMIC_RELAXED, __HIP_MEMORY_SCOPE_AGENT);
}
__device__ __forceinline__ int aloadi(const int* p){
  return __hip_atomic_load(p, __ATOMIC_RELAXED, __HIP_MEMORY_SCOPE_AGENT);
}
__device__ __forceinline__ void astorei(int* p, int v){
  __hip_atomic_store(p, v, __ATOMIC_RELAXED, __HIP_MEMORY_SCOPE_AGENT);
}

// ---- prototypes (unchanged): parallel ordered compaction.
__global__ __launch_bounds__(256) void proto_kernel(
    const float* __restrict__ fs, const int* __restrict__ ys,
    float* __restrict__ Pt, float* __restrict__ pn)
{
  const int c = blockIdx.x, t = threadIdx.x;
  __shared__ int list[N_S];
  __shared__ int pref[256];
  __shared__ int lcount;

  int loc[7]; int cnt = 0;
  const int base = t * 7;                  // 256*7 = 1792 >= 1600
  #pragma unroll
  for (int u = 0; u < 7; u++){
    const int i = base + u;
    if (i < N_S && ys[i] == c) loc[cnt++] = i;
  }
  pref[t] = cnt;
  __syncthreads();
  for (int off = 1; off < 256; off <<= 1){
    int v = (t >= off) ? pref[t - off] : 0;
    __syncthreads();
    pref[t] += v;
    __syncthreads();
  }
  const int start = pref[t] - cnt;
  for (int u = 0; u < cnt; u++) list[start + u] = loc[u];
  if (t == 255) lcount = pref[255];
  __syncthreads();

  const int n = lcount;
  float a0 = 0.f, a1 = 0.f, a2 = 0.f, a3 = 0.f;
  for (int m = 0; m < n; m++){
    const float* r = fs + (size_t)list[m] * DIM;
    a0 += r[t]; a1 += r[t + 256]; a2 += r[t + 512]; a3 += r[t + 768];
  }
  const float inv = 1.0f / fmaxf((float)n, 1.0f);
  const float v0 = a0*inv, v1 = a1*inv, v2 = a2*inv, v3 = a3*inv;
  Pt[(t      )*N_C + c] = v0;
  Pt[(t + 256)*N_C + c] = v1;
  Pt[(t + 512)*N_C + c] = v2;
  Pt[(t + 768)*N_C + c] = v3;
  __shared__ float red[256];
  red[t] = v0*v0 + v1*v1 + v2*v2 + v3*v3;
  __syncthreads();
  for (int o = 128; o; o >>= 1){ if (t < o) red[t] += red[t + o]; __syncthreads(); }
  if (t == 0) pn[c] = red[0];
}

// ---- fused per-row sqnorm + fp32 -> (f16 hi, f16 lo) split (unchanged).
__global__ __launch_bounds__(256) void prep_kernel(
    const float* __restrict__ X, float* __restrict__ qn,
    _Float16* __restrict__ Xh, _Float16* __restrict__ Xl)
{
  const int i = blockIdx.x, t = threadIdx.x;
  const float* r = X + (size_t)i * DIM;
  const float v0 = r[t], v1 = r[t+256], v2 = r[t+512], v3 = r[t+768];
  const size_t b = (size_t)i * DIM;
  _Float16 h0 = (_Float16)v0, h1 = (_Float16)v1, h2 = (_Float16)v2, h3 = (_Float16)v3;
  Xh[b + t      ] = h0; Xl[b + t      ] = (_Float16)(v0 - (float)h0);
  Xh[b + t + 256] = h1; Xl[b + t + 256] = (_Float16)(v1 - (float)h1);
  Xh[b + t + 512] = h2; Xl[b + t + 512] = (_Float16)(v2 - (float)h2);
  Xh[b + t + 768] = h3; Xl[b + t + 768] = (_Float16)(v3 - (float)h3);
  __shared__ float red[256];
  red[t] = v0*v0 + v1*v1 + v2*v2 + v3*v3;
  __syncthreads();
  for (int o = 128; o; o >>= 1){ if (t < o) red[t] += red[t + o]; __syncthreads(); }
  if (t == 0) qn[i] = red[0];
}

// ---- pairwise distances via f16 split-precision MFMA (XCD swizzle kept).
__global__ __launch_bounds__(256, 3) void dist_mfma(
    const _Float16* __restrict__ Xh, const _Float16* __restrict__ Xl,
    const float* __restrict__ qn, float* __restrict__ Dq)
{
  const int t = threadIdx.x, w = t >> 6, l = t & 63;
  const int lb  = blockIdx.y * 32 + blockIdx.x;   // dispatch-linear id
  const int xcd = lb & 7, k = lb >> 3;            // round-robin XCD map
  const int bxs = xcd * 4 + (k >> 5);             // 4 col-blocks per XCD
  const int bys = k & 31;
  const int i0 = bys * 128 + (w >> 1) * 64;
  const int j0 = bxs * 128 + (w & 1) * 64;
  const int fr = l & 15;
  const int kq = (l >> 4) * 8;

  f4 acc[4][4];
  #pragma unroll
  for (int a = 0; a < 4; a++)
    #pragma unroll
    for (int b = 0; b < 4; b++) acc[a][b] = (f4){0.f, 0.f, 0.f, 0.f};

  const _Float16* pAh = Xh + (size_t)(i0 + fr) * DIM + kq;
  const _Float16* pAl = Xl + (size_t)(i0 + fr) * DIM + kq;
  const _Float16* pBh = Xh + (size_t)(j0 + fr) * DIM + kq;
  const _Float16* pBl = Xl + (size_t)(j0 + fr) * DIM + kq;

  #pragma unroll 1
  for (int k0 = 0; k0 < DIM; k0 += 32){
    h8 ah[4], al[4];
    #pragma unroll
    for (int sm = 0; sm < 4; sm++){
      const size_t o = (size_t)(sm * 16) * DIM + k0;
      ah[sm] = *(const h8*)(pAh + o);
      al[sm] = *(const h8*)(pAl + o);
    }
    #pragma unroll
    for (int sn = 0; sn < 4; sn++){
      const size_t o = (size_t)(sn * 16) * DIM + k0;
      h8 bh = *(const h8*)(pBh + o);
      h8 bl = *(const h8*)(pBl + o);
      #pragma unroll
      for (int sm = 0; sm < 4; sm++){
        acc[sm][sn] = __builtin_amdgcn_mfma_f32_16x16x32_f16(ah[sm], bh, acc[sm][sn], 0, 0, 0);
        acc[sm][sn] = __builtin_amdgcn_mfma_f32_16x16x32_f16(ah[sm], bl, acc[sm][sn], 0, 0, 0);
        acc[sm][sn] = __builtin_amdgcn_mfma_f32_16x16x32_f16(al[sm], bh, acc[sm][sn], 0, 0, 0);
      }
    }
  }

  const int cr = (l >> 4) * 4;
  const int cc = l & 15;
  #pragma unroll
  for (int sm = 0; sm < 4; sm++){
    #pragma unroll
    for (int r = 0; r < 4; r++){
      const int row = i0 + sm * 16 + cr + r;
      const float qi = qn[row];
      float* dstrow = &Dq[(size_t)row * N_Q];
      #pragma unroll
      for (int sn = 0; sn < 4; sn++){
        const int col = j0 + sn * 16 + cc;
        float d2 = qi + qn[col] - 2.0f * acc[sm][sn][r];
        dstrow[col] = sqrtf(fmaxf(d2, 0.f));
      }
    }
  }
}

// ---- per-row 13 smallest (ties -> smaller index), row in registers (unchanged).
__global__ __launch_bounds__(256) void topk_kernel(
    const float* __restrict__ Dq, int* __restrict__ nbr,
    float* __restrict__ dnbr, float* __restrict__ sigma)
{
  const int i = blockIdx.x, t = threadIdx.x;
  const float* row = Dq + (size_t)i * N_Q;
  float r[16];
  #pragma unroll
  for (int u = 0; u < 16; u++) r[u] = row[t + u * 256];

  __shared__ float pvf[4];
  __shared__ int   pif[4];
  __shared__ int   bwi_s;

  for (int s = 0; s < KNN + 1; s++){
    float best = FLT_MAX; int bj = 0x7fffffff;
    #pragma unroll
    for (int u = 0; u < 16; u++){
      float v = r[u];
      if (v < best){ best = v; bj = t + u * 256; }
    }
    #pragma unroll
    for (int o = 32; o; o >>= 1){
      float ov = __shfl_xor(best, o, 64); int oj = __shfl_xor(bj, o, 64);
      if (ov < best || (ov == best && oj < bj)){ best = ov; bj = oj; }
    }
    if ((t & 63) == 0){ pvf[t >> 6] = best; pif[t >> 6] = bj; }
    __syncthreads();
    if (t == 0){
      float bv = pvf[0]; int bi2 = pif[0];
      #pragma unroll
      for (int w2 = 1; w2 < 4; w2++){
        float v2 = pvf[w2]; int i2 = pif[w2];
        if (v2 < bv || (v2 == bv && i2 < bi2)){ bv = v2; bi2 = i2; }
      }
      bwi_s = bi2;
      if (s >= 1){ nbr[i*KNN + s - 1] = bi2; dnbr[i*KNN + s - 1] = bv; }
      if (s == KNN) sigma[i] = bv + 1e-8f;
    }
    __syncthreads();
    const int widx = bwi_s;
    if ((widx & 255) == t) r[widx >> 8] = FLT_MAX;
  }
}

// ============ hierarchical monotonic grid barrier (setup + final phases) ============
__device__ __forceinline__ void gbar_leader(int* garr, int* gcnt, int* gen, int target){
  const int g = blockIdx.x >> 4;
  int old = __hip_atomic_fetch_add(&garr[g * 32], 1, __ATOMIC_RELAXED, __HIP_MEMORY_SCOPE_AGENT);
  if ((old & 15) == 15){
    int o2 = __hip_atomic_fetch_add(gcnt, 1, __ATOMIC_RELAXED, __HIP_MEMORY_SCOPE_AGENT);
    if ((o2 & 15) == 15)
      __hip_atomic_fetch_add(gen, 1, __ATOMIC_RELAXED, __HIP_MEMORY_SCOPE_AGENT);
  }
  while (__hip_atomic_load(gen, __ATOMIC_RELAXED, __HIP_MEMORY_SCOPE_AGENT) < target)
    __builtin_amdgcn_s_sleep(1);
}

// ---- chunked SpMV (R17, unchanged): K groups of 8 edges, all loads issue
//      concurrently, then the fma sequence runs in the exact old order.
template<int K>
__device__ __forceinline__ void chunk_fma(
    const float* __restrict__ src, const int2* adj, int gbase, int lane,
    float& s0, float& s1, float& s2, float& s3,
    float& s4, float& s5, float& s6, float& s7)
{
  float yv[K][8], wv[K][8];
  #pragma unroll
  for (int g = 0; g < K; g++){
    #pragma unroll
    for (int u = 0; u < 8; u++){
      int2 a = adj[(gbase + g) * 8 + u];
      wv[g][u] = __int_as_float(a.y);
      yv[g][u] = aload(&src[a.x + lane]);
    }
  }
  #pragma unroll
  for (int g = 0; g < K; g++){
    s0 = fmaf(wv[g][0], yv[g][0], s0);
    s1 = fmaf(wv[g][1], yv[g][1], s1);
    s2 = fmaf(wv[g][2], yv[g][2], s2);
    s3 = fmaf(wv[g][3], yv[g][3], s3);
    s4 = fmaf(wv[g][4], yv[g][4], s4);
    s5 = fmaf(wv[g][5], yv[g][5], s5);
    s6 = fmaf(wv[g][6], yv[g][6], s6);
    s7 = fmaf(wv[g][7], yv[g][7], s7);
  }
}

__device__ __forceinline__ float spmv_row(
    const float* __restrict__ src, const int2* adj,
    const int* __restrict__ colA, const float* __restrict__ wA,
    int p0, int p1v, int lane)
{
  const int deg  = p1v - p0;
  const int ncap = deg < ADJ_CAP ? deg : ADJ_CAP;
  const int nfull = ncap & ~7;
  const int ng = nfull >> 3;
  float s0=0.f,s1=0.f,s2=0.f,s3=0.f,s4=0.f,s5=0.f,s6=0.f,s7=0.f;

  int g = 0;
  #pragma unroll 1
  for (; g + 4 <= ng; g += 4){
    chunk_fma<4>(src, adj, g, lane, s0,s1,s2,s3,s4,s5,s6,s7);
  }
  {
    const int left = ng - g;
    if (left == 3)      chunk_fma<3>(src, adj, g, lane, s0,s1,s2,s3,s4,s5,s6,s7);
    else if (left == 2) chunk_fma<2>(src, adj, g, lane, s0,s1,s2,s3,s4,s5,s6,s7);
    else if (left == 1) chunk_fma<1>(src, adj, g, lane, s0,s1,s2,s3,s4,s5,s6,s7);
  }

  if (deg > ADJ_CAP){
    int qg = p0 + ADJ_CAP;
    for (; qg + 8 <= p1v; qg += 8){
      s0 = fmaf(wA[qg    ], aload(&src[colA[qg    ] + lane]), s0);
      s1 = fmaf(wA[qg + 1], aload(&src[colA[qg + 1] + lane]), s1);
      s2 = fmaf(wA[qg + 2], aload(&src[colA[qg + 2] + lane]), s2);
      s3 = fmaf(wA[qg + 3], aload(&src[colA[qg + 3] + lane]), s3);
      s4 = fmaf(wA[qg + 4], aload(&src[colA[qg + 4] + lane]), s4);
      s5 = fmaf(wA[qg + 5], aload(&src[colA[qg + 5] + lane]), s5);
      s6 = fmaf(wA[qg + 6], aload(&src[colA[qg + 6] + lane]), s6);
      s7 = fmaf(wA[qg + 7], aload(&src[colA[qg + 7] + lane]), s7);
    }
    for (; qg < p1v; qg++)
      s0 = fmaf(wA[qg], aload(&src[colA[qg] + lane]), s0);
  } else {
    const int rem = deg - nfull;            // 0..7
    if (rem > 0){
      float yr[7], wr[7];
      #pragma unroll
      for (int u = 0; u < 7; u++){
        if (u < rem){
          int2 a = adj[nfull + u];
          wr[u] = __int_as_float(a.y);
          yr[u] = aload(&src[a.x + lane]);
        }
      }
      #pragma unroll
      for (int u = 0; u < 7; u++)
        if (u < rem) s0 = fmaf(wr[u], yr[u], s0);
    }
  }
  return ((s0+s1)+(s2+s3)) + ((s4+s5)+(s6+s7));
}

// ---- R18: per-row version poll. Row j's slot-k values are readable once
//      ver[j] >= k+1 (producer does s_waitcnt(0) before publishing, same
//      drain-then-flag pattern as the proven pbar). Ring slots are never
//      overwritten -> no tearing. Lane u covers neighbor u and u+64; deg>128
//      tail (if ever) handled serially by lane 0.
__device__ __forceinline__ void poll_nbrs(
    const int* ver, int j0, int j1, int need,
    const int* __restrict__ colA, int p0, int deg, int lane)
{
  while (1){
    bool ok = true;
    if (j0 >= 0) ok = ok && (aloadi(&ver[j0]) >= need);
    if (j1 >= 0) ok = ok && (aloadi(&ver[j1]) >= need);
    if (deg > 128 && lane == 0){
      for (int u = 128; u < deg; u++){
        int j = colA[p0 + u] >> 6;
        ok = ok && (aloadi(&ver[j]) >= need);
      }
    }
    if (__all(ok)) break;
    __builtin_amdgcn_s_sleep(1);
  }
}

// ---- fused tail. R18: NO per-iteration grid barrier. All 51 y-iterates go
//      into a ring (aliasing the retired Dq buffer); each row publishes a
//      version after its stores drain; consumers poll only their ~25
//      neighbors' versions and free-run. Convergence iteration T is
//      reconstructed exactly afterwards from per-k delta maxima (identical
//      to the while-loop's exit condition); output = argmax of ring[T].
//      Every y_k comes from the bit-identical fmaf chain -> same output.
__global__ __launch_bounds__(1024, 4) void tail_loop(
    const float* __restrict__ Xq, const float* __restrict__ Pt,
    const float* __restrict__ pn, const float* __restrict__ qn,
    const int* __restrict__ nbr, const float* __restrict__ dnbr,
    const float* __restrict__ sigma,
    float* d2min, float* denom, float* wh,
    float* rowsum, int* indeg, int* rowptr, int* fillc,
    int* colA, float* wA,
    float* ring, int* ver, int* deltab, int* Tg,
    int* gcnt, int* gen, int* garr, int* __restrict__ out)
{
  __shared__ union {
    float pchunk[CHK * N_C];                // 64 KB, P0a staging
    struct {
      int   ipart[1024];
      int   hist[1024];
      float cand[4096];
      int   candn, b1s, b2s;
    } s;
  } U;
  __shared__ int2  adjL[16 * ADJ_CAP];      // 12 KB, per-wave adjacency
  __shared__ int   dmaxS[64];               // per-block per-k delta max (bits)
  __shared__ int   Tsh;

  const int tid  = threadIdx.x;
  const int lane = tid & 63;
  const int wv   = tid >> 6;
  const int row  = blockIdx.x * 16 + wv;
  if (tid < 64) dmaxS[tid] = 0;             // deltas >= 0 -> int-compare safe

  // ---------- P0a: a-row via LDS-staged Pt chunks (bit-exact dp order) ----------
  const float* xr = Xq + (size_t)row * DIM;
  const f4*    xr4 = (const f4*)xr;
  float dp[8];
  #pragma unroll
  for (int u = 0; u < 8; u++) dp[u] = 0.f;

  for (int f0 = 0; f0 < DIM; f0 += CHK){
    const f4* srcv = (const f4*)(Pt + (size_t)f0 * N_C);
    f4* dstv = (f4*)U.pchunk;
    #pragma unroll
    for (int u = 0; u < 4; u++) dstv[tid + u * 1024] = srcv[tid + u * 1024];
    __syncthreads();
    #pragma unroll 1
    for (int f = 0; f < CHK; f += 8){
      const f4 xa = xr4[(f0 + f) >> 2];
      const f4 xb = xr4[((f0 + f) >> 2) + 1];
      const float* pc = U.pchunk + f * N_C + lane;
      dp[0] = fmaf(xa[0], pc[0      ], dp[0]);
      dp[1] = fmaf(xa[1], pc[N_C    ], dp[1]);
      dp[2] = fmaf(xa[2], pc[N_C * 2], dp[2]);
      dp[3] = fmaf(xa[3], pc[N_C * 3], dp[3]);
      dp[4] = fmaf(xb[0], pc[N_C * 4], dp[4]);
      dp[5] = fmaf(xb[1], pc[N_C * 5], dp[5]);
      dp[6] = fmaf(xb[2], pc[N_C * 6], dp[6]);
      dp[7] = fmaf(xb[3], pc[N_C * 7], dp[7]);
    }
    __syncthreads();                        // before next chunk overwrite
  }
  const float dot = ((dp[0]+dp[1])+(dp[2]+dp[3])) + ((dp[4]+dp[5])+(dp[6]+dp[7]));
  const float av  = fmaxf(qn[row] + pn[lane] - 2.0f * dot, 0.0f);
  const float d2m = wave_min64(av);
  if (lane == 0) astore(&d2min[row], d2m);

  // ---------- P0b: edge weights + degrees ----------
  const int e = blockIdx.x * 1024 + tid;
  if (e < N_Q * KNN){
    const int i = e / KNN;
    const int j = nbr[e];
    float wgt = 0.5f * expf(-dnbr[e] / (sigma[i] * sigma[j]));
    astore(&wh[e], wgt);
    atomicAdd(&rowsum[i], wgt);
    atomicAdd(&rowsum[j], wgt);
    atomicAdd(&indeg[j], 1);
  }

  __syncthreads();
  if (tid == 0) gbar_leader(garr, gcnt, gen, 1);
  __syncthreads();

  // ---------- P1: y0 -> ring slot 0 + ver=1; scan (blk 0) + median (blk 1) ----------
  float xv = -av;
  float m = wave_max64(xv), ee = expf(xv - m), ss = wave_sum64(ee);
  float prev = ee / ss;                    // y0
  astore(&ring[(size_t)row * N_C + lane], prev);
  if (lane == 0) astorei(&ver[row], 1);    // visibility via phase-3 fences

  if (blockIdx.x == 0){
    int* ipart = U.s.ipart;
    const int base = tid * 4;
    int c0 = aloadi(&indeg[base]),     c1 = aloadi(&indeg[base + 1]);
    int c2 = aloadi(&indeg[base + 2]), c3 = aloadi(&indeg[base + 3]);
    const int s4 = c0 + c1 + c2 + c3;
    ipart[tid] = s4;
    __syncthreads();
    for (int off = 1; off < 1024; off <<= 1){
      int v = (tid >= off) ? ipart[tid - off] : 0;
      __syncthreads();
      ipart[tid] += v;
      __syncthreads();
    }
    int run = ipart[tid] - s4;
    astorei(&rowptr[base    ], KNN * (base    ) + run); run += c0;
    astorei(&rowptr[base + 1], KNN * (base + 1) + run); run += c1;
    astorei(&rowptr[base + 2], KNN * (base + 2) + run); run += c2;
    astorei(&rowptr[base + 3], KNN * (base + 3) + run);
    if (tid == 1023) astorei(&rowptr[N_Q], KNN * N_Q + ipart[1023]);
  }
  if (blockIdx.x == 1){
    int*   hist = U.s.hist;
    float* cand = U.s.cand;
    const int base = tid * 4;
    float dv[4];
    #pragma unroll
    for (int u = 0; u < 4; u++) dv[u] = sqrtf(aload(&d2min[base + u]));
    float mn = fminf(fminf(dv[0], dv[1]), fminf(dv[2], dv[3]));
    float mx = fmaxf(fmaxf(dv[0], dv[1]), fmaxf(dv[2], dv[3]));
    mn = wave_min64(mn); mx = wave_max64(mx);
    if (lane == 0){ cand[wv] = mn; cand[wv + 16] = mx; }
    __syncthreads();
    if (tid == 0){
      float a = cand[0], b = cand[16];
      for (int k = 1; k < 16; k++){ a = fminf(a, cand[k]); b = fmaxf(b, cand[16 + k]); }
      cand[32] = a; cand[33] = b;
    }
    __syncthreads();
    mn = cand[32]; mx = cand[33];
    const float rng = mx - mn;
    const float scale = (rng > 0.f) ? (1024.0f / rng) : 0.f;
    hist[tid] = 0;
    __syncthreads();
    int bidx[4];
    #pragma unroll
    for (int u = 0; u < 4; u++){
      int b = (int)((dv[u] - mn) * scale);
      b = b < 0 ? 0 : (b > 1023 ? 1023 : b);
      bidx[u] = b;
      atomicAdd(&hist[b], 1);
    }
    __syncthreads();
    for (int off = 1; off < 1024; off <<= 1){
      int v = (tid >= off) ? hist[tid - off] : 0;
      __syncthreads();
      hist[tid] += v;
      __syncthreads();
    }
    if (hist[tid] >= 2048 && (tid == 0 || hist[tid - 1] < 2048)) U.s.b1s = tid;
    if (hist[tid] >= 2049 && (tid == 0 || hist[tid - 1] < 2049)) U.s.b2s = tid;
    if (tid == 0) U.s.candn = 0;
    __syncthreads();
    const int b1 = U.s.b1s, b2 = U.s.b2s;
    const int cntBefore = (b1 > 0) ? hist[b1 - 1] : 0;
    #pragma unroll
    for (int u = 0; u < 4; u++){
      if (bidx[u] >= b1 && bidx[u] <= b2){
        int pos = atomicAdd(&U.s.candn, 1);
        cand[pos] = dv[u];
      }
    }
    __syncthreads();
    const int mcnt = U.s.candn;
    int P = 2; while (P < mcnt) P <<= 1;
    for (int i2 = mcnt + tid; i2 < P; i2 += 1024) cand[i2] = FLT_MAX;
    __syncthreads();
    for (int k = 2; k <= P; k <<= 1){
      for (int st = k >> 1; st > 0; st >>= 1){
        for (int i2 = tid; i2 < P; i2 += 1024){
          int j2 = i2 ^ st;
          if (j2 > i2){
            float a2 = cand[i2], b3 = cand[j2];
            bool up = ((i2 & k) == 0);
            if (up ? (a2 > b3) : (a2 < b3)){ cand[i2] = b3; cand[j2] = a2; }
          }
        }
        __syncthreads();
      }
    }
    if (tid == 0){
      float v1 = cand[2047 - cntBefore], v2 = cand[2048 - cntBefore];
      float med = 0.5f * (v1 + v2);
      astore(denom, 2.0f * med * med + 1e-8f);
    }
  }

  __syncthreads();
  if (tid == 0) gbar_leader(garr, gcnt, gen, 2);
  __syncthreads();

  // ---------- P2: CSR fill + per-row coef ----------
  if (e < N_Q * KNN){
    const int i = e / KNN, tt = e % KNN;
    const int j = nbr[e];
    const float wgt = aload(&wh[e]);
    const int p = aloadi(&rowptr[i]) + tt;
    colA[p] = j * N_C; wA[p] = wgt;
    const int q = aloadi(&rowptr[j]) + KNN + atomicAdd(&fillc[j], 1);
    colA[q] = i * N_C; wA[q] = wgt;
  }
  const float cf = expf(-d2m / aload(denom)) / (aload(&rowsum[row]) + 1e-8f);
  const int p0  = aloadi(&rowptr[row]);
  const int p1v = aloadi(&rowptr[row + 1]);

  __builtin_amdgcn_fence(__ATOMIC_RELEASE, "agent");
  __syncthreads();
  if (tid == 0) gbar_leader(garr, gcnt, gen, 3);
  __syncthreads();
  __builtin_amdgcn_fence(__ATOMIC_ACQUIRE, "agent");

  // ---------- preload loop-invariant adjacency into LDS ----------
  const int deg  = p1v - p0;
  const int ncap = deg < ADJ_CAP ? deg : ADJ_CAP;
  for (int u = lane; u < ncap; u += 64)
    adjL[wv * ADJ_CAP + u] = make_int2(colA[p0 + u], __float_as_int(wA[p0 + u]));
  __syncthreads();
  const int2* adj = adjL + wv * ADJ_CAP;

  // poll registers: lane u covers neighbors u and u+64
  int j0 = -1, j1 = -1;
  if (lane < deg)
    j0 = ((lane < ncap) ? adj[lane].x : colA[p0 + lane]) >> 6;
  if (lane + 64 < deg)
    j1 = ((lane + 64 < ncap) ? adj[lane + 64].x : colA[p0 + lane + 64]) >> 6;

  // ---------- free-run dataflow loop: k = 0..49, y_{k+1} = step(y_k) ----------
  #pragma unroll 1
  for (int k = 0; k < MAX_ITER; k++){
    poll_nbrs(ver, j0, j1, k + 1, colA, p0, deg, lane);
    const float* src = ring + (size_t)k * (N_Q * N_C);
    float sum = spmv_row(src, adj, colA, wA, p0, p1v, lane);
    float xv2 = -av + cf * sum;
    float mm = wave_max64(xv2), e2 = expf(xv2 - mm), ss2 = wave_sum64(e2);
    float nxt = e2 / ss2;
    astore(&ring[((size_t)(k + 1) * N_Q + row) * N_C + lane], nxt);
    float dm = wave_max64(fabsf(nxt - prev));
    if (lane == 0) atomicMax(&dmaxS[k], __float_as_int(dm));
    __builtin_amdgcn_s_waitcnt(0);          // drain this wave's y stores
    if (lane == 0) astorei(&ver[row], k + 2);
    prev = nxt;
  }

  // ---------- epilogue: reconstruct T, output argmax(ring[T]) ----------
  __syncthreads();                          // all waves of block done
  if (tid < MAX_ITER) astorei(&deltab[tid * NBLK + blockIdx.x], dmaxS[tid]);
  __builtin_amdgcn_fence(__ATOMIC_RELEASE, "agent");
  __syncthreads();
  if (tid == 0) gbar_leader(garr, gcnt, gen, 4);
  __syncthreads();
  __builtin_amdgcn_fence(__ATOMIC_ACQUIRE, "agent");

  if (blockIdx.x == 0){
    if (tid < MAX_ITER){
      int mx = 0;
      #pragma unroll 4
      for (int b = 0; b < NBLK; b++)
        mx = max(mx, aloadi(&deltab[tid * NBLK + b]));
      U.s.ipart[tid] = (__int_as_float(mx) < EPS_CONV) ? 1 : 0;
    }
    __syncthreads();
    if (tid == 0){
      int T = MAX_ITER;
      for (int k2 = 0; k2 < MAX_ITER; k2++)
        if (U.s.ipart[k2]){ T = k2; break; }
      astorei(Tg, T + 1);
    }
  }
  if (tid == 0){
    int tv;
    while ((tv = aloadi(Tg)) == 0) __builtin_amdgcn_s_sleep(1);
    Tsh = tv - 1;
  }
  __syncthreads();
  const int T = Tsh;

  float bv = aload(&ring[((size_t)T * N_Q + row) * N_C + lane]);
  int bi = lane;
  #pragma unroll
  for (int o = 32; o; o >>= 1){
    float ov = __shfl_xor(bv, o, 64); int oi = __shfl_xor(bi, o, 64);
    if (ov > bv || (ov == bv && oi < bi)){ bv = ov; bi = oi; }
  }
  if (lane == 0) out[row] = bi;
}

extern "C" void kernel_launch(void* const* d_in, const int* in_sizes, int n_in,
                              void* d_out, int out_size, void* d_ws, size_t ws_size,
                              hipStream_t stream)
{
  const float* feat_s = (const float*)d_in[0];
  const int*   y_s    = (const int*)d_in[1];
  const float* feat_q = (const float*)d_in[2];
  int* out = (int*)d_out;

  char* wp = (char*)d_ws;
  auto alloc = [&](size_t bytes) -> char* {
    char* p = wp;
    wp += (bytes + 255) & ~(size_t)255;
    return p;
  };
  float*     Dq  = (float*)alloc((size_t)N_Q * N_Q * 4);     // 64 MB; ring aliases this
  _Float16*  Xh  = (_Float16*)alloc((size_t)N_Q * DIM * 2);  // 8 MB
  _Float16*  Xl  = (_Float16*)alloc((size_t)N_Q * DIM * 2);  // 8 MB
  float* Pt     = (float*)alloc((size_t)DIM * N_C * 4);
  float* pn     = (float*)alloc(N_C * 4);
  float* qn     = (float*)alloc(N_Q * 4);
  float* d2min  = (float*)alloc(N_Q * 4);
  float* denom  = (float*)alloc(256);
  int*   nbr    = (int*)alloc((size_t)N_Q * KNN * 4);
  float* dnbr   = (float*)alloc((size_t)N_Q * KNN * 4);
  float* sigma  = (float*)alloc(N_Q * 4);
  float* wh     = (float*)alloc((size_t)N_Q * KNN * 4);
  int*   rowptr = (int*)alloc((N_Q + 1) * 4);
  int*   colA   = (int*)alloc((size_t)2 * N_Q * KNN * 4);
  float* wA     = (float*)alloc((size_t)2 * N_Q * KNN * 4);
  int*   deltab = (int*)alloc((size_t)MAX_ITER * NBLK * 4);  // [k][block] delta bits
  // zero-region: rowsum | indeg | fillc | syncw | garr | ver | Tg
  const size_t zbytes = (size_t)N_Q*12 + 256 + 2048 + (size_t)N_Q*4 + 256;
  char*  zbase  = alloc(zbytes);
  float* rowsum = (float*)(zbase);
  int*   indeg  = (int*)(zbase + N_Q*4);
  int*   fillc  = (int*)(zbase + N_Q*8);
  int*   syncw  = (int*)(zbase + N_Q*12);
  int*   garr   = (int*)(zbase + N_Q*12 + 256);
  int*   ver    = (int*)(zbase + N_Q*12 + 256 + 2048);
  int*   Tg     = (int*)(zbase + N_Q*12 + 256 + 2048 + N_Q*4);

  hipMemsetAsync(zbase, 0, zbytes, stream);

  proto_kernel <<<N_C, 256, 0, stream>>>(feat_s, y_s, Pt, pn);
  prep_kernel  <<<N_Q, 256, 0, stream>>>(feat_q, qn, Xh, Xl);
  dist_mfma    <<<dim3(N_Q/128, N_Q/128), 256, 0, stream>>>(Xh, Xl, qn, Dq);
  topk_kernel  <<<N_Q, 256, 0, stream>>>(Dq, nbr, dnbr, sigma);

  int* gcnt = &syncw[0];
  int* gen  = &syncw[32];
  const float* Xq = feat_q;
  float* ring = Dq;   // 51 slots x 1 MB = 51 MB <= 64 MB; Dq retired after topk
  void* args[] = {&Xq, &Pt, &pn, &qn, &nbr, &dnbr, &sigma,
                  &d2min, &denom, &wh, &rowsum, &indeg, &rowptr, &fillc,
                  &colA, &wA, &ring, &ver, &deltab, &Tg,
                  &gcnt, &gen, &garr, &out};
  hipLaunchCooperativeKernel((void*)tail_loop, dim3(NBLK), dim3(1024), args, 0, stream);
}

// Round 6
// 8587.843 us; speedup vs baseline: 2.1309x; 2.1309x over previous
//
#include <hip/hip_runtime.h>
#include <hip/hip_cooperative_groups.h>
#include <cfloat>
#include <cmath>

#define N_Q 4096
#define N_S 1600
#define DIM 1024
#define N_C 64
#define KNN 12
#define MAX_ITER 50
#define EPS_CONV 1e-4f
#define NBLK 256         // tail_loop grid size
#define ADJ_CAP 96       // per-row LDS adjacency capacity (multiple of 8)
#define CHK 256          // P0a: Pt features staged per LDS chunk

typedef _Float16 h8 __attribute__((ext_vector_type(8)));
typedef float    f4 __attribute__((ext_vector_type(4)));

__device__ __forceinline__ float wave_max64(float v){
  #pragma unroll
  for (int o = 32; o; o >>= 1) v = fmaxf(v, __shfl_xor(v, o, 64));
  return v;
}
__device__ __forceinline__ float wave_sum64(float v){
  #pragma unroll
  for (int o = 32; o; o >>= 1) v += __shfl_xor(v, o, 64);
  return v;
}
__device__ __forceinline__ float wave_min64(float v){
  #pragma unroll
  for (int o = 32; o; o >>= 1) v = fminf(v, __shfl_xor(v, o, 64));
  return v;
}

// coherent (device-visible) element accesses for cross-block-communicated data
__device__ __forceinline__ float aload(const float* p){
  return __hip_atomic_load(p, __ATOMIC_RELAXED, __HIP_MEMORY_SCOPE_AGENT);
}
__device__ __forceinline__ void astore(float* p, float v){
  __hip_atomic_store(p, v, __ATOMIC_RELAXED, __HIP_MEMORY_SCOPE_AGENT);
}
__device__ __forceinline__ int aloadi(const int* p){
  return __hip_atomic_load(p, __ATOMIC_RELAXED, __HIP_MEMORY_SCOPE_AGENT);
}
__device__ __forceinline__ void astorei(int* p, int v){
  __hip_atomic_store(p, v, __ATOMIC_RELAXED, __HIP_MEMORY_SCOPE_AGENT);
}

// ---- prototypes (unchanged): parallel ordered compaction.
__global__ __launch_bounds__(256) void proto_kernel(
    const float* __restrict__ fs, const int* __restrict__ ys,
    float* __restrict__ Pt, float* __restrict__ pn)
{
  const int c = blockIdx.x, t = threadIdx.x;
  __shared__ int list[N_S];
  __shared__ int pref[256];
  __shared__ int lcount;

  int loc[7]; int cnt = 0;
  const int base = t * 7;                  // 256*7 = 1792 >= 1600
  #pragma unroll
  for (int u = 0; u < 7; u++){
    const int i = base + u;
    if (i < N_S && ys[i] == c) loc[cnt++] = i;
  }
  pref[t] = cnt;
  __syncthreads();
  for (int off = 1; off < 256; off <<= 1){
    int v = (t >= off) ? pref[t - off] : 0;
    __syncthreads();
    pref[t] += v;
    __syncthreads();
  }
  const int start = pref[t] - cnt;
  for (int u = 0; u < cnt; u++) list[start + u] = loc[u];
  if (t == 255) lcount = pref[255];
  __syncthreads();

  const int n = lcount;
  float a0 = 0.f, a1 = 0.f, a2 = 0.f, a3 = 0.f;
  for (int m = 0; m < n; m++){
    const float* r = fs + (size_t)list[m] * DIM;
    a0 += r[t]; a1 += r[t + 256]; a2 += r[t + 512]; a3 += r[t + 768];
  }
  const float inv = 1.0f / fmaxf((float)n, 1.0f);
  const float v0 = a0*inv, v1 = a1*inv, v2 = a2*inv, v3 = a3*inv;
  Pt[(t      )*N_C + c] = v0;
  Pt[(t + 256)*N_C + c] = v1;
  Pt[(t + 512)*N_C + c] = v2;
  Pt[(t + 768)*N_C + c] = v3;
  __shared__ float red[256];
  red[t] = v0*v0 + v1*v1 + v2*v2 + v3*v3;
  __syncthreads();
  for (int o = 128; o; o >>= 1){ if (t < o) red[t] += red[t + o]; __syncthreads(); }
  if (t == 0) pn[c] = red[0];
}

// ---- fused per-row sqnorm + fp32 -> (f16 hi, f16 lo) split (unchanged).
__global__ __launch_bounds__(256) void prep_kernel(
    const float* __restrict__ X, float* __restrict__ qn,
    _Float16* __restrict__ Xh, _Float16* __restrict__ Xl)
{
  const int i = blockIdx.x, t = threadIdx.x;
  const float* r = X + (size_t)i * DIM;
  const float v0 = r[t], v1 = r[t+256], v2 = r[t+512], v3 = r[t+768];
  const size_t b = (size_t)i * DIM;
  _Float16 h0 = (_Float16)v0, h1 = (_Float16)v1, h2 = (_Float16)v2, h3 = (_Float16)v3;
  Xh[b + t      ] = h0; Xl[b + t      ] = (_Float16)(v0 - (float)h0);
  Xh[b + t + 256] = h1; Xl[b + t + 256] = (_Float16)(v1 - (float)h1);
  Xh[b + t + 512] = h2; Xl[b + t + 512] = (_Float16)(v2 - (float)h2);
  Xh[b + t + 768] = h3; Xl[b + t + 768] = (_Float16)(v3 - (float)h3);
  __shared__ float red[256];
  red[t] = v0*v0 + v1*v1 + v2*v2 + v3*v3;
  __syncthreads();
  for (int o = 128; o; o >>= 1){ if (t < o) red[t] += red[t + o]; __syncthreads(); }
  if (t == 0) qn[i] = red[0];
}

// ---- pairwise distances via f16 split-precision MFMA (XCD swizzle kept).
__global__ __launch_bounds__(256, 3) void dist_mfma(
    const _Float16* __restrict__ Xh, const _Float16* __restrict__ Xl,
    const float* __restrict__ qn, float* __restrict__ Dq)
{
  const int t = threadIdx.x, w = t >> 6, l = t & 63;
  const int lb  = blockIdx.y * 32 + blockIdx.x;   // dispatch-linear id
  const int xcd = lb & 7, k = lb >> 3;            // round-robin XCD map
  const int bxs = xcd * 4 + (k >> 5);             // 4 col-blocks per XCD
  const int bys = k & 31;
  const int i0 = bys * 128 + (w >> 1) * 64;
  const int j0 = bxs * 128 + (w & 1) * 64;
  const int fr = l & 15;
  const int kq = (l >> 4) * 8;

  f4 acc[4][4];
  #pragma unroll
  for (int a = 0; a < 4; a++)
    #pragma unroll
    for (int b = 0; b < 4; b++) acc[a][b] = (f4){0.f, 0.f, 0.f, 0.f};

  const _Float16* pAh = Xh + (size_t)(i0 + fr) * DIM + kq;
  const _Float16* pAl = Xl + (size_t)(i0 + fr) * DIM + kq;
  const _Float16* pBh = Xh + (size_t)(j0 + fr) * DIM + kq;
  const _Float16* pBl = Xl + (size_t)(j0 + fr) * DIM + kq;

  #pragma unroll 1
  for (int k0 = 0; k0 < DIM; k0 += 32){
    h8 ah[4], al[4];
    #pragma unroll
    for (int sm = 0; sm < 4; sm++){
      const size_t o = (size_t)(sm * 16) * DIM + k0;
      ah[sm] = *(const h8*)(pAh + o);
      al[sm] = *(const h8*)(pAl + o);
    }
    #pragma unroll
    for (int sn = 0; sn < 4; sn++){
      const size_t o = (size_t)(sn * 16) * DIM + k0;
      h8 bh = *(const h8*)(pBh + o);
      h8 bl = *(const h8*)(pBl + o);
      #pragma unroll
      for (int sm = 0; sm < 4; sm++){
        acc[sm][sn] = __builtin_amdgcn_mfma_f32_16x16x32_f16(ah[sm], bh, acc[sm][sn], 0, 0, 0);
        acc[sm][sn] = __builtin_amdgcn_mfma_f32_16x16x32_f16(ah[sm], bl, acc[sm][sn], 0, 0, 0);
        acc[sm][sn] = __builtin_amdgcn_mfma_f32_16x16x32_f16(al[sm], bh, acc[sm][sn], 0, 0, 0);
      }
    }
  }

  const int cr = (l >> 4) * 4;
  const int cc = l & 15;
  #pragma unroll
  for (int sm = 0; sm < 4; sm++){
    #pragma unroll
    for (int r = 0; r < 4; r++){
      const int row = i0 + sm * 16 + cr + r;
      const float qi = qn[row];
      float* dstrow = &Dq[(size_t)row * N_Q];
      #pragma unroll
      for (int sn = 0; sn < 4; sn++){
        const int col = j0 + sn * 16 + cc;
        float d2 = qi + qn[col] - 2.0f * acc[sm][sn][r];
        dstrow[col] = sqrtf(fmaxf(d2, 0.f));
      }
    }
  }
}

// ---- per-row 13 smallest (ties -> smaller index), row in registers (unchanged).
__global__ __launch_bounds__(256) void topk_kernel(
    const float* __restrict__ Dq, int* __restrict__ nbr,
    float* __restrict__ dnbr, float* __restrict__ sigma)
{
  const int i = blockIdx.x, t = threadIdx.x;
  const float* row = Dq + (size_t)i * N_Q;
  float r[16];
  #pragma unroll
  for (int u = 0; u < 16; u++) r[u] = row[t + u * 256];

  __shared__ float pvf[4];
  __shared__ int   pif[4];
  __shared__ int   bwi_s;

  for (int s = 0; s < KNN + 1; s++){
    float best = FLT_MAX; int bj = 0x7fffffff;
    #pragma unroll
    for (int u = 0; u < 16; u++){
      float v = r[u];
      if (v < best){ best = v; bj = t + u * 256; }
    }
    #pragma unroll
    for (int o = 32; o; o >>= 1){
      float ov = __shfl_xor(best, o, 64); int oj = __shfl_xor(bj, o, 64);
      if (ov < best || (ov == best && oj < bj)){ best = ov; bj = oj; }
    }
    if ((t & 63) == 0){ pvf[t >> 6] = best; pif[t >> 6] = bj; }
    __syncthreads();
    if (t == 0){
      float bv = pvf[0]; int bi2 = pif[0];
      #pragma unroll
      for (int w2 = 1; w2 < 4; w2++){
        float v2 = pvf[w2]; int i2 = pif[w2];
        if (v2 < bv || (v2 == bv && i2 < bi2)){ bv = v2; bi2 = i2; }
      }
      bwi_s = bi2;
      if (s >= 1){ nbr[i*KNN + s - 1] = bi2; dnbr[i*KNN + s - 1] = bv; }
      if (s == KNN) sigma[i] = bv + 1e-8f;
    }
    __syncthreads();
    const int widx = bwi_s;
    if ((widx & 255) == t) r[widx >> 8] = FLT_MAX;
  }
}

// ============ hierarchical monotonic grid barrier (setup + final phases) ============
__device__ __forceinline__ void gbar_leader(int* garr, int* gcnt, int* gen, int target){
  const int g = blockIdx.x >> 4;
  int old = __hip_atomic_fetch_add(&garr[g * 32], 1, __ATOMIC_RELAXED, __HIP_MEMORY_SCOPE_AGENT);
  if ((old & 15) == 15){
    int o2 = __hip_atomic_fetch_add(gcnt, 1, __ATOMIC_RELAXED, __HIP_MEMORY_SCOPE_AGENT);
    if ((o2 & 15) == 15)
      __hip_atomic_fetch_add(gen, 1, __ATOMIC_RELAXED, __HIP_MEMORY_SCOPE_AGENT);
  }
  while (__hip_atomic_load(gen, __ATOMIC_RELAXED, __HIP_MEMORY_SCOPE_AGENT) < target)
    __builtin_amdgcn_s_sleep(1);
}

// ---- chunked SpMV (R17, unchanged): K groups of 8 edges, all loads issue
//      concurrently, then the fma sequence runs in the exact old order.
template<int K>
__device__ __forceinline__ void chunk_fma(
    const float* __restrict__ src, const int2* adj, int gbase, int lane,
    float& s0, float& s1, float& s2, float& s3,
    float& s4, float& s5, float& s6, float& s7)
{
  float yv[K][8], wv[K][8];
  #pragma unroll
  for (int g = 0; g < K; g++){
    #pragma unroll
    for (int u = 0; u < 8; u++){
      int2 a = adj[(gbase + g) * 8 + u];
      wv[g][u] = __int_as_float(a.y);
      yv[g][u] = aload(&src[a.x + lane]);
    }
  }
  #pragma unroll
  for (int g = 0; g < K; g++){
    s0 = fmaf(wv[g][0], yv[g][0], s0);
    s1 = fmaf(wv[g][1], yv[g][1], s1);
    s2 = fmaf(wv[g][2], yv[g][2], s2);
    s3 = fmaf(wv[g][3], yv[g][3], s3);
    s4 = fmaf(wv[g][4], yv[g][4], s4);
    s5 = fmaf(wv[g][5], yv[g][5], s5);
    s6 = fmaf(wv[g][6], yv[g][6], s6);
    s7 = fmaf(wv[g][7], yv[g][7], s7);
  }
}

__device__ __forceinline__ float spmv_row(
    const float* __restrict__ src, const int2* adj,
    const int* __restrict__ colA, const float* __restrict__ wA,
    int p0, int p1v, int lane)
{
  const int deg  = p1v - p0;
  const int ncap = deg < ADJ_CAP ? deg : ADJ_CAP;
  const int nfull = ncap & ~7;
  const int ng = nfull >> 3;
  float s0=0.f,s1=0.f,s2=0.f,s3=0.f,s4=0.f,s5=0.f,s6=0.f,s7=0.f;

  int g = 0;
  #pragma unroll 1
  for (; g + 4 <= ng; g += 4){
    chunk_fma<4>(src, adj, g, lane, s0,s1,s2,s3,s4,s5,s6,s7);
  }
  {
    const int left = ng - g;
    if (left == 3)      chunk_fma<3>(src, adj, g, lane, s0,s1,s2,s3,s4,s5,s6,s7);
    else if (left == 2) chunk_fma<2>(src, adj, g, lane, s0,s1,s2,s3,s4,s5,s6,s7);
    else if (left == 1) chunk_fma<1>(src, adj, g, lane, s0,s1,s2,s3,s4,s5,s6,s7);
  }

  if (deg > ADJ_CAP){
    int qg = p0 + ADJ_CAP;
    for (; qg + 8 <= p1v; qg += 8){
      s0 = fmaf(wA[qg    ], aload(&src[colA[qg    ] + lane]), s0);
      s1 = fmaf(wA[qg + 1], aload(&src[colA[qg + 1] + lane]), s1);
      s2 = fmaf(wA[qg + 2], aload(&src[colA[qg + 2] + lane]), s2);
      s3 = fmaf(wA[qg + 3], aload(&src[colA[qg + 3] + lane]), s3);
      s4 = fmaf(wA[qg + 4], aload(&src[colA[qg + 4] + lane]), s4);
      s5 = fmaf(wA[qg + 5], aload(&src[colA[qg + 5] + lane]), s5);
      s6 = fmaf(wA[qg + 6], aload(&src[colA[qg + 6] + lane]), s6);
      s7 = fmaf(wA[qg + 7], aload(&src[colA[qg + 7] + lane]), s7);
    }
    for (; qg < p1v; qg++)
      s0 = fmaf(wA[qg], aload(&src[colA[qg] + lane]), s0);
  } else {
    const int rem = deg - nfull;            // 0..7
    if (rem > 0){
      float yr[7], wr[7];
      #pragma unroll
      for (int u = 0; u < 7; u++){
        if (u < rem){
          int2 a = adj[nfull + u];
          wr[u] = __int_as_float(a.y);
          yr[u] = aload(&src[a.x + lane]);
        }
      }
      #pragma unroll
      for (int u = 0; u < 7; u++)
        if (u < rem) s0 = fmaf(wr[u], yr[u], s0);
    }
  }
  return ((s0+s1)+(s2+s3)) + ((s4+s5)+(s6+s7));
}

// ---- R19: block-granular dependency poll. Block B's flag >= k means ALL
//      of B's 16 rows have y_k drained to LLC (flag is stored by tid0 only
//      after the block-wide __syncthreads vmcnt drain -> the R13-R17-proven
//      publish pattern, 256 stores/iter, NOT R18's per-row 4096-store storm).
//      A wave polls only the <=25 blocks owning its row's neighbors.
__device__ __forceinline__ void poll_deps(
    const int* bflag, int jb0, int jb1, int need,
    const int* __restrict__ colA, int p0, int deg)
{
  while (1){
    bool ok = true;
    if (jb0 >= 0) ok = ok && (aloadi(&bflag[jb0]) >= need);
    if (jb1 >= 0) ok = ok && (aloadi(&bflag[jb1]) >= need);
    if (deg > 128){
      for (int u = 128; u < deg; u++){
        int jb = colA[p0 + u] >> 10;        // (j*64)>>10 = j/16 = block id
        ok = ok && (aloadi(&bflag[jb]) >= need);
      }
    }
    if (__all(ok)) break;
    __builtin_amdgcn_s_sleep(1);
  }
}

// ---- fused tail. R19: dataflow at BLOCK granularity. 51-slot y-ring
//      (aliasing retired Dq, slots never overwritten -> bounded drift is
//      harmless); per-block monotone flags published post-__syncthreads
//      (proven drain-then-flag); waves poll only their neighbor-owning
//      blocks. Exit iteration T reconstructed exactly from per-k delta
//      maxima (identical to the while-loop's condition, proven in R18's
//      passing run); output argmax(ring[T]). fmaf chains bit-identical.
__global__ __launch_bounds__(1024, 4) void tail_loop(
    const float* __restrict__ Xq, const float* __restrict__ Pt,
    const float* __restrict__ pn, const float* __restrict__ qn,
    const int* __restrict__ nbr, const float* __restrict__ dnbr,
    const float* __restrict__ sigma,
    float* d2min, float* denom, float* wh,
    float* rowsum, int* indeg, int* rowptr, int* fillc,
    int* colA, float* wA,
    float* ring, int* bflag, int* deltab, int* Tg,
    int* gcnt, int* gen, int* garr, int* __restrict__ out)
{
  __shared__ union {
    float pchunk[CHK * N_C];                // 64 KB, P0a staging
    struct {
      int   ipart[1024];
      int   hist[1024];
      float cand[4096];
      int   candn, b1s, b2s;
    } s;
  } U;
  __shared__ int2  adjL[16 * ADJ_CAP];      // 12 KB, per-wave adjacency
  __shared__ int   dmaxS[64];               // per-block per-k delta max (bits)
  __shared__ int   Tsh;

  const int tid  = threadIdx.x;
  const int lane = tid & 63;
  const int wv   = tid >> 6;
  const int row  = blockIdx.x * 16 + wv;
  if (tid < 64) dmaxS[tid] = 0;             // deltas >= 0 -> int-compare safe

  // ---------- P0a: a-row via LDS-staged Pt chunks (bit-exact dp order) ----------
  const float* xr = Xq + (size_t)row * DIM;
  const f4*    xr4 = (const f4*)xr;
  float dp[8];
  #pragma unroll
  for (int u = 0; u < 8; u++) dp[u] = 0.f;

  for (int f0 = 0; f0 < DIM; f0 += CHK){
    const f4* srcv = (const f4*)(Pt + (size_t)f0 * N_C);
    f4* dstv = (f4*)U.pchunk;
    #pragma unroll
    for (int u = 0; u < 4; u++) dstv[tid + u * 1024] = srcv[tid + u * 1024];
    __syncthreads();
    #pragma unroll 1
    for (int f = 0; f < CHK; f += 8){
      const f4 xa = xr4[(f0 + f) >> 2];
      const f4 xb = xr4[((f0 + f) >> 2) + 1];
      const float* pc = U.pchunk + f * N_C + lane;
      dp[0] = fmaf(xa[0], pc[0      ], dp[0]);
      dp[1] = fmaf(xa[1], pc[N_C    ], dp[1]);
      dp[2] = fmaf(xa[2], pc[N_C * 2], dp[2]);
      dp[3] = fmaf(xa[3], pc[N_C * 3], dp[3]);
      dp[4] = fmaf(xb[0], pc[N_C * 4], dp[4]);
      dp[5] = fmaf(xb[1], pc[N_C * 5], dp[5]);
      dp[6] = fmaf(xb[2], pc[N_C * 6], dp[6]);
      dp[7] = fmaf(xb[3], pc[N_C * 7], dp[7]);
    }
    __syncthreads();                        // before next chunk overwrite
  }
  const float dot = ((dp[0]+dp[1])+(dp[2]+dp[3])) + ((dp[4]+dp[5])+(dp[6]+dp[7]));
  const float av  = fmaxf(qn[row] + pn[lane] - 2.0f * dot, 0.0f);
  const float d2m = wave_min64(av);
  if (lane == 0) astore(&d2min[row], d2m);

  // ---------- P0b: edge weights + degrees ----------
  const int e = blockIdx.x * 1024 + tid;
  if (e < N_Q * KNN){
    const int i = e / KNN;
    const int j = nbr[e];
    float wgt = 0.5f * expf(-dnbr[e] / (sigma[i] * sigma[j]));
    astore(&wh[e], wgt);
    atomicAdd(&rowsum[i], wgt);
    atomicAdd(&rowsum[j], wgt);
    atomicAdd(&indeg[j], 1);
  }

  __syncthreads();
  if (tid == 0) gbar_leader(garr, gcnt, gen, 1);
  __syncthreads();

  // ---------- P1: y0 -> ring slot 0; scan (blk 0) + median (blk 1) ----------
  float xv = -av;
  float m = wave_max64(xv), ee = expf(xv - m), ss = wave_sum64(ee);
  float prevv = ee / ss;                   // y0
  astore(&ring[(size_t)row * N_C + lane], prevv);

  if (blockIdx.x == 0){
    int* ipart = U.s.ipart;
    const int base = tid * 4;
    int c0 = aloadi(&indeg[base]),     c1 = aloadi(&indeg[base + 1]);
    int c2 = aloadi(&indeg[base + 2]), c3 = aloadi(&indeg[base + 3]);
    const int s4 = c0 + c1 + c2 + c3;
    ipart[tid] = s4;
    __syncthreads();
    for (int off = 1; off < 1024; off <<= 1){
      int v = (tid >= off) ? ipart[tid - off] : 0;
      __syncthreads();
      ipart[tid] += v;
      __syncthreads();
    }
    int run = ipart[tid] - s4;
    astorei(&rowptr[base    ], KNN * (base    ) + run); run += c0;
    astorei(&rowptr[base + 1], KNN * (base + 1) + run); run += c1;
    astorei(&rowptr[base + 2], KNN * (base + 2) + run); run += c2;
    astorei(&rowptr[base + 3], KNN * (base + 3) + run);
    if (tid == 1023) astorei(&rowptr[N_Q], KNN * N_Q + ipart[1023]);
  }
  if (blockIdx.x == 1){
    int*   hist = U.s.hist;
    float* cand = U.s.cand;
    const int base = tid * 4;
    float dv[4];
    #pragma unroll
    for (int u = 0; u < 4; u++) dv[u] = sqrtf(aload(&d2min[base + u]));
    float mn = fminf(fminf(dv[0], dv[1]), fminf(dv[2], dv[3]));
    float mx = fmaxf(fmaxf(dv[0], dv[1]), fmaxf(dv[2], dv[3]));
    mn = wave_min64(mn); mx = wave_max64(mx);
    if (lane == 0){ cand[wv] = mn; cand[wv + 16] = mx; }
    __syncthreads();
    if (tid == 0){
      float a = cand[0], b = cand[16];
      for (int k = 1; k < 16; k++){ a = fminf(a, cand[k]); b = fmaxf(b, cand[16 + k]); }
      cand[32] = a; cand[33] = b;
    }
    __syncthreads();
    mn = cand[32]; mx = cand[33];
    const float rng = mx - mn;
    const float scale = (rng > 0.f) ? (1024.0f / rng) : 0.f;
    hist[tid] = 0;
    __syncthreads();
    int bidx[4];
    #pragma unroll
    for (int u = 0; u < 4; u++){
      int b = (int)((dv[u] - mn) * scale);
      b = b < 0 ? 0 : (b > 1023 ? 1023 : b);
      bidx[u] = b;
      atomicAdd(&hist[b], 1);
    }
    __syncthreads();
    for (int off = 1; off < 1024; off <<= 1){
      int v = (tid >= off) ? hist[tid - off] : 0;
      __syncthreads();
      hist[tid] += v;
      __syncthreads();
    }
    if (hist[tid] >= 2048 && (tid == 0 || hist[tid - 1] < 2048)) U.s.b1s = tid;
    if (hist[tid] >= 2049 && (tid == 0 || hist[tid - 1] < 2049)) U.s.b2s = tid;
    if (tid == 0) U.s.candn = 0;
    __syncthreads();
    const int b1 = U.s.b1s, b2 = U.s.b2s;
    const int cntBefore = (b1 > 0) ? hist[b1 - 1] : 0;
    #pragma unroll
    for (int u = 0; u < 4; u++){
      if (bidx[u] >= b1 && bidx[u] <= b2){
        int pos = atomicAdd(&U.s.candn, 1);
        cand[pos] = dv[u];
      }
    }
    __syncthreads();
    const int mcnt = U.s.candn;
    int P = 2; while (P < mcnt) P <<= 1;
    for (int i2 = mcnt + tid; i2 < P; i2 += 1024) cand[i2] = FLT_MAX;
    __syncthreads();
    for (int k = 2; k <= P; k <<= 1){
      for (int st = k >> 1; st > 0; st >>= 1){
        for (int i2 = tid; i2 < P; i2 += 1024){
          int j2 = i2 ^ st;
          if (j2 > i2){
            float a2 = cand[i2], b3 = cand[j2];
            bool up = ((i2 & k) == 0);
            if (up ? (a2 > b3) : (a2 < b3)){ cand[i2] = b3; cand[j2] = a2; }
          }
        }
        __syncthreads();
      }
    }
    if (tid == 0){
      float v1 = cand[2047 - cntBefore], v2 = cand[2048 - cntBefore];
      float med = 0.5f * (v1 + v2);
      astore(denom, 2.0f * med * med + 1e-8f);
    }
  }

  __syncthreads();
  if (tid == 0) gbar_leader(garr, gcnt, gen, 2);
  __syncthreads();

  // ---------- P2: CSR fill + per-row coef ----------
  if (e < N_Q * KNN){
    const int i = e / KNN, tt = e % KNN;
    const int j = nbr[e];
    const float wgt = aload(&wh[e]);
    const int p = aloadi(&rowptr[i]) + tt;
    colA[p] = j * N_C; wA[p] = wgt;
    const int q = aloadi(&rowptr[j]) + KNN + atomicAdd(&fillc[j], 1);
    colA[q] = i * N_C; wA[q] = wgt;
  }
  const float cf = expf(-d2m / aload(denom)) / (aload(&rowsum[row]) + 1e-8f);
  const int p0  = aloadi(&rowptr[row]);
  const int p1v = aloadi(&rowptr[row + 1]);

  __builtin_amdgcn_fence(__ATOMIC_RELEASE, "agent");
  __syncthreads();
  if (tid == 0) gbar_leader(garr, gcnt, gen, 3);
  __syncthreads();
  __builtin_amdgcn_fence(__ATOMIC_ACQUIRE, "agent");

  // ---------- preload loop-invariant adjacency into LDS ----------
  const int deg  = p1v - p0;
  const int ncap = deg < ADJ_CAP ? deg : ADJ_CAP;
  for (int u = lane; u < ncap; u += 64)
    adjL[wv * ADJ_CAP + u] = make_int2(colA[p0 + u], __float_as_int(wA[p0 + u]));
  __syncthreads();
  const int2* adj = adjL + wv * ADJ_CAP;

  // poll registers: lane u covers neighbor-BLOCKS of edges u and u+64
  int jb0 = -1, jb1 = -1;
  if (lane < deg)
    jb0 = ((lane < ncap) ? adj[lane].x : colA[p0 + lane]) >> 10;
  if (lane + 64 < deg)
    jb1 = ((lane + 64 < ncap) ? adj[lane + 64].x : colA[p0 + lane + 64]) >> 10;

  // ---------- dataflow loop: k = 0..49, y_{k+1} = step(y_k) ----------
  // y0 visibility: phase-3 release/acquire fences; bflag init 0 = "slot 0 ready".
  #pragma unroll 1
  for (int k = 0; k < MAX_ITER; k++){
    poll_deps(bflag, jb0, jb1, k, colA, p0, deg);
    const float* src = ring + (size_t)k * (N_Q * N_C);
    float sum = spmv_row(src, adj, colA, wA, p0, p1v, lane);
    float xv2 = -av + cf * sum;
    float mm = wave_max64(xv2), e2 = expf(xv2 - mm), ss2 = wave_sum64(e2);
    float nxt = e2 / ss2;
    astore(&ring[((size_t)(k + 1) * N_Q + row) * N_C + lane], nxt);
    float dm = wave_max64(fabsf(nxt - prevv));
    if (lane == 0) atomicMax(&dmaxS[k], __float_as_int(dm));
    __syncthreads();                        // all 16 waves' y stores drained
    if (tid == 0){
      __builtin_amdgcn_s_waitcnt(0);
      astorei(&bflag[blockIdx.x], k + 1);   // slot k+1 ready (whole block)
    }
    prevv = nxt;
  }

  // ---------- epilogue: reconstruct T, output argmax(ring[T]) ----------
  __syncthreads();
  if (tid < MAX_ITER) astorei(&deltab[tid * NBLK + blockIdx.x], dmaxS[tid]);
  __builtin_amdgcn_fence(__ATOMIC_RELEASE, "agent");
  __syncthreads();
  if (tid == 0) gbar_leader(garr, gcnt, gen, 4);
  __syncthreads();
  __builtin_amdgcn_fence(__ATOMIC_ACQUIRE, "agent");

  if (blockIdx.x == 0){
    if (tid < MAX_ITER){
      int mx = 0;
      #pragma unroll 4
      for (int b = 0; b < NBLK; b++)
        mx = max(mx, aloadi(&deltab[tid * NBLK + b]));
      U.s.ipart[tid] = (__int_as_float(mx) < EPS_CONV) ? 1 : 0;
    }
    __syncthreads();
    if (tid == 0){
      int T = MAX_ITER;
      for (int k2 = 0; k2 < MAX_ITER; k2++)
        if (U.s.ipart[k2]){ T = k2; break; }
      astorei(Tg, T + 1);
    }
  }
  if (tid == 0){
    int tv;
    while ((tv = aloadi(Tg)) == 0) __builtin_amdgcn_s_sleep(1);
    Tsh = tv - 1;
  }
  __syncthreads();
  const int T = Tsh;

  float bv = aload(&ring[((size_t)T * N_Q + row) * N_C + lane]);
  int bi = lane;
  #pragma unroll
  for (int o = 32; o; o >>= 1){
    float ov = __shfl_xor(bv, o, 64); int oi = __shfl_xor(bi, o, 64);
    if (ov > bv || (ov == bv && oi < bi)){ bv = ov; bi = oi; }
  }
  if (lane == 0) out[row] = bi;
}

extern "C" void kernel_launch(void* const* d_in, const int* in_sizes, int n_in,
                              void* d_out, int out_size, void* d_ws, size_t ws_size,
                              hipStream_t stream)
{
  const float* feat_s = (const float*)d_in[0];
  const int*   y_s    = (const int*)d_in[1];
  const float* feat_q = (const float*)d_in[2];
  int* out = (int*)d_out;

  char* wp = (char*)d_ws;
  auto alloc = [&](size_t bytes) -> char* {
    char* p = wp;
    wp += (bytes + 255) & ~(size_t)255;
    return p;
  };
  float*     Dq  = (float*)alloc((size_t)N_Q * N_Q * 4);     // 64 MB; ring aliases this
  _Float16*  Xh  = (_Float16*)alloc((size_t)N_Q * DIM * 2);  // 8 MB
  _Float16*  Xl  = (_Float16*)alloc((size_t)N_Q * DIM * 2);  // 8 MB
  float* Pt     = (float*)alloc((size_t)DIM * N_C * 4);
  float* pn     = (float*)alloc(N_C * 4);
  float* qn     = (float*)alloc(N_Q * 4);
  float* d2min  = (float*)alloc(N_Q * 4);
  float* denom  = (float*)alloc(256);
  int*   nbr    = (int*)alloc((size_t)N_Q * KNN * 4);
  float* dnbr   = (float*)alloc((size_t)N_Q * KNN * 4);
  float* sigma  = (float*)alloc(N_Q * 4);
  float* wh     = (float*)alloc((size_t)N_Q * KNN * 4);
  int*   rowptr = (int*)alloc((N_Q + 1) * 4);
  int*   colA   = (int*)alloc((size_t)2 * N_Q * KNN * 4);
  float* wA     = (float*)alloc((size_t)2 * N_Q * KNN * 4);
  int*   deltab = (int*)alloc((size_t)MAX_ITER * NBLK * 4);  // [k][block] delta bits
  // zero-region: rowsum | indeg | fillc | syncw | garr | bflag | Tg
  const size_t zbytes = (size_t)N_Q*12 + 256 + 2048 + NBLK*4 + 256;
  char*  zbase  = alloc(zbytes);
  float* rowsum = (float*)(zbase);
  int*   indeg  = (int*)(zbase + N_Q*4);
  int*   fillc  = (int*)(zbase + N_Q*8);
  int*   syncw  = (int*)(zbase + N_Q*12);
  int*   garr   = (int*)(zbase + N_Q*12 + 256);
  int*   bflag  = (int*)(zbase + N_Q*12 + 256 + 2048);
  int*   Tg     = (int*)(zbase + N_Q*12 + 256 + 2048 + NBLK*4);

  hipMemsetAsync(zbase, 0, zbytes, stream);

  proto_kernel <<<N_C, 256, 0, stream>>>(feat_s, y_s, Pt, pn);
  prep_kernel  <<<N_Q, 256, 0, stream>>>(feat_q, qn, Xh, Xl);
  dist_mfma    <<<dim3(N_Q/128, N_Q/128), 256, 0, stream>>>(Xh, Xl, qn, Dq);
  topk_kernel  <<<N_Q, 256, 0, stream>>>(Dq, nbr, dnbr, sigma);

  int* gcnt = &syncw[0];
  int* gen  = &syncw[32];
  const float* Xq = feat_q;
  float* ring = Dq;   // 51 slots x 1 MB = 51 MB <= 64 MB; Dq retired after topk
  void* args[] = {&Xq, &Pt, &pn, &qn, &nbr, &dnbr, &sigma,
                  &d2min, &denom, &wh, &rowsum, &indeg, &rowptr, &fillc,
                  &colA, &wA, &ring, &bflag, &deltab, &Tg,
                  &gcnt, &gen, &garr, &out};
  hipLaunchCooperativeKernel((void*)tail_loop, dim3(NBLK), dim3(1024), args, 0, stream);
}

// Round 7
// 476.283 us; speedup vs baseline: 38.4215x; 18.0310x over previous
//
#include <hip/hip_runtime.h>
#include <hip/hip_cooperative_groups.h>
#include <cfloat>
#include <cmath>

#define N_Q 4096
#define N_S 1600
#define DIM 1024
#define N_C 64
#define KNN 12
#define MAX_ITER 50
#define EPS_CONV 1e-4f
#define NBLK 256         // tail_loop grid size
#define ADJ_CAP 96       // per-row LDS adjacency capacity (multiple of 8)
#define CHK 256          // P0a: Pt features staged per LDS chunk
#define DPAD 40          // dist_mfma LDS k-stride (f16): 32 + 8 pad -> ~2-way banks

typedef _Float16 h8 __attribute__((ext_vector_type(8)));
typedef float    f4 __attribute__((ext_vector_type(4)));

__device__ __forceinline__ float wave_max64(float v){
  #pragma unroll
  for (int o = 32; o; o >>= 1) v = fmaxf(v, __shfl_xor(v, o, 64));
  return v;
}
__device__ __forceinline__ float wave_sum64(float v){
  #pragma unroll
  for (int o = 32; o; o >>= 1) v += __shfl_xor(v, o, 64);
  return v;
}
__device__ __forceinline__ float wave_min64(float v){
  #pragma unroll
  for (int o = 32; o; o >>= 1) v = fminf(v, __shfl_xor(v, o, 64));
  return v;
}

// coherent (device-visible) element accesses for cross-block-communicated data
__device__ __forceinline__ float aload(const float* p){
  return __hip_atomic_load(p, __ATOMIC_RELAXED, __HIP_MEMORY_SCOPE_AGENT);
}
__device__ __forceinline__ void astore(float* p, float v){
  __hip_atomic_store(p, v, __ATOMIC_RELAXED, __HIP_MEMORY_SCOPE_AGENT);
}
__device__ __forceinline__ int aloadi(const int* p){
  return __hip_atomic_load(p, __ATOMIC_RELAXED, __HIP_MEMORY_SCOPE_AGENT);
}
__device__ __forceinline__ void astorei(int* p, int v){
  __hip_atomic_store(p, v, __ATOMIC_RELAXED, __HIP_MEMORY_SCOPE_AGENT);
}
__device__ __forceinline__ unsigned long long aload64(const unsigned long long* p){
  return __hip_atomic_load(p, __ATOMIC_RELAXED, __HIP_MEMORY_SCOPE_AGENT);
}
__device__ __forceinline__ void astore64(unsigned long long* p, unsigned long long v){
  __hip_atomic_store(p, v, __ATOMIC_RELAXED, __HIP_MEMORY_SCOPE_AGENT);
}

// ---- prototypes (unchanged): parallel ordered compaction.
__global__ __launch_bounds__(256) void proto_kernel(
    const float* __restrict__ fs, const int* __restrict__ ys,
    float* __restrict__ Pt, float* __restrict__ pn)
{
  const int c = blockIdx.x, t = threadIdx.x;
  __shared__ int list[N_S];
  __shared__ int pref[256];
  __shared__ int lcount;

  int loc[7]; int cnt = 0;
  const int base = t * 7;                  // 256*7 = 1792 >= 1600
  #pragma unroll
  for (int u = 0; u < 7; u++){
    const int i = base + u;
    if (i < N_S && ys[i] == c) loc[cnt++] = i;
  }
  pref[t] = cnt;
  __syncthreads();
  for (int off = 1; off < 256; off <<= 1){
    int v = (t >= off) ? pref[t - off] : 0;
    __syncthreads();
    pref[t] += v;
    __syncthreads();
  }
  const int start = pref[t] - cnt;
  for (int u = 0; u < cnt; u++) list[start + u] = loc[u];
  if (t == 255) lcount = pref[255];
  __syncthreads();

  const int n = lcount;
  float a0 = 0.f, a1 = 0.f, a2 = 0.f, a3 = 0.f;
  for (int m = 0; m < n; m++){
    const float* r = fs + (size_t)list[m] * DIM;
    a0 += r[t]; a1 += r[t + 256]; a2 += r[t + 512]; a3 += r[t + 768];
  }
  const float inv = 1.0f / fmaxf((float)n, 1.0f);
  const float v0 = a0*inv, v1 = a1*inv, v2 = a2*inv, v3 = a3*inv;
  Pt[(t      )*N_C + c] = v0;
  Pt[(t + 256)*N_C + c] = v1;
  Pt[(t + 512)*N_C + c] = v2;
  Pt[(t + 768)*N_C + c] = v3;
  __shared__ float red[256];
  red[t] = v0*v0 + v1*v1 + v2*v2 + v3*v3;
  __syncthreads();
  for (int o = 128; o; o >>= 1){ if (t < o) red[t] += red[t + o]; __syncthreads(); }
  if (t == 0) pn[c] = red[0];
}

// ---- fused per-row sqnorm + fp32 -> (f16 hi, f16 lo) split (unchanged).
__global__ __launch_bounds__(256) void prep_kernel(
    const float* __restrict__ X, float* __restrict__ qn,
    _Float16* __restrict__ Xh, _Float16* __restrict__ Xl)
{
  const int i = blockIdx.x, t = threadIdx.x;
  const float* r = X + (size_t)i * DIM;
  const float v0 = r[t], v1 = r[t+256], v2 = r[t+512], v3 = r[t+768];
  const size_t b = (size_t)i * DIM;
  _Float16 h0 = (_Float16)v0, h1 = (_Float16)v1, h2 = (_Float16)v2, h3 = (_Float16)v3;
  Xh[b + t      ] = h0; Xl[b + t      ] = (_Float16)(v0 - (float)h0);
  Xh[b + t + 256] = h1; Xl[b + t + 256] = (_Float16)(v1 - (float)h1);
  Xh[b + t + 512] = h2; Xl[b + t + 512] = (_Float16)(v2 - (float)h2);
  Xh[b + t + 768] = h3; Xl[b + t + 768] = (_Float16)(v3 - (float)h3);
  __shared__ float red[256];
  red[t] = v0*v0 + v1*v1 + v2*v2 + v3*v3;
  __syncthreads();
  for (int o = 128; o; o >>= 1){ if (t < o) red[t] += red[t + o]; __syncthreads(); }
  if (t == 0) qn[i] = red[0];
}

// ---- pairwise distances via f16 split-precision MFMA.
//      R20: block-level LDS staging. Each 128x128 block stages its A/B
//      hi+lo 32-k slabs once per k-iter (40KB LDS, +8-f16 pad -> ~2-way
//      banks), replacing 4 redundant per-wave global reads with 1. The
//      staged values are COPIES: each output's MFMA sequence (k0 order,
//      3-MFMA order, fr/kq lane mapping) is unchanged -> Dq bit-identical.
//      XCD swizzle kept.
__global__ __launch_bounds__(256, 3) void dist_mfma(
    const _Float16* __restrict__ Xh, const _Float16* __restrict__ Xl,
    const float* __restrict__ qn, float* __restrict__ Dq)
{
  __shared__ __align__(16) _Float16 As[2][128][DPAD];  // [hi/lo][row][k] 20KB
  __shared__ __align__(16) _Float16 Bs[2][128][DPAD];  // 20KB

  const int t = threadIdx.x, w = t >> 6, l = t & 63;
  const int lb  = blockIdx.y * 32 + blockIdx.x;   // dispatch-linear id
  const int xcd = lb & 7, k = lb >> 3;            // round-robin XCD map
  const int bxs = xcd * 4 + (k >> 5);             // 4 col-blocks per XCD
  const int bys = k & 31;
  const int bi0 = bys * 128, bj0 = bxs * 128;
  const int i0w = (w >> 1) * 64;                  // wave sub-tile in block
  const int j0w = (w & 1) * 64;
  const int fr = l & 15;
  const int kq = (l >> 4) * 8;

  // staging: thread t covers row (t>>1), 32B segment (t&1)
  const int srow = t >> 1;
  const int sseg = (t & 1) * 16;                  // f16 offset within row

  f4 acc[4][4];
  #pragma unroll
  for (int a = 0; a < 4; a++)
    #pragma unroll
    for (int b = 0; b < 4; b++) acc[a][b] = (f4){0.f, 0.f, 0.f, 0.f};

  const size_t abase = (size_t)(bi0 + srow) * DIM + sseg;
  const size_t bbase = (size_t)(bj0 + srow) * DIM + sseg;

  #pragma unroll 1
  for (int k0 = 0; k0 < DIM; k0 += 32){
    // issue all 8 staging loads before the barrier (in flight during wait)
    h8 va0 = *(const h8*)(Xh + abase + k0);
    h8 va1 = *(const h8*)(Xh + abase + k0 + 8);
    h8 vb0 = *(const h8*)(Xl + abase + k0);
    h8 vb1 = *(const h8*)(Xl + abase + k0 + 8);
    h8 vc0 = *(const h8*)(Xh + bbase + k0);
    h8 vc1 = *(const h8*)(Xh + bbase + k0 + 8);
    h8 vd0 = *(const h8*)(Xl + bbase + k0);
    h8 vd1 = *(const h8*)(Xl + bbase + k0 + 8);
    __syncthreads();                      // prev iter's LDS reads complete
    *(h8*)&As[0][srow][sseg    ] = va0;
    *(h8*)&As[0][srow][sseg + 8] = va1;
    *(h8*)&As[1][srow][sseg    ] = vb0;
    *(h8*)&As[1][srow][sseg + 8] = vb1;
    *(h8*)&Bs[0][srow][sseg    ] = vc0;
    *(h8*)&Bs[0][srow][sseg + 8] = vc1;
    *(h8*)&Bs[1][srow][sseg    ] = vd0;
    *(h8*)&Bs[1][srow][sseg + 8] = vd1;
    __syncthreads();                      // tiles ready

    h8 ah[4], al[4];
    #pragma unroll
    for (int sm = 0; sm < 4; sm++){
      ah[sm] = *(const h8*)&As[0][i0w + sm * 16 + fr][kq];
      al[sm] = *(const h8*)&As[1][i0w + sm * 16 + fr][kq];
    }
    #pragma unroll
    for (int sn = 0; sn < 4; sn++){
      h8 bh = *(const h8*)&Bs[0][j0w + sn * 16 + fr][kq];
      h8 bl = *(const h8*)&Bs[1][j0w + sn * 16 + fr][kq];
      #pragma unroll
      for (int sm = 0; sm < 4; sm++){
        acc[sm][sn] = __builtin_amdgcn_mfma_f32_16x16x32_f16(ah[sm], bh, acc[sm][sn], 0, 0, 0);
        acc[sm][sn] = __builtin_amdgcn_mfma_f32_16x16x32_f16(ah[sm], bl, acc[sm][sn], 0, 0, 0);
        acc[sm][sn] = __builtin_amdgcn_mfma_f32_16x16x32_f16(al[sm], bh, acc[sm][sn], 0, 0, 0);
      }
    }
  }

  const int i0 = bi0 + i0w;
  const int j0 = bj0 + j0w;
  const int cr = (l >> 4) * 4;
  const int cc = l & 15;
  #pragma unroll
  for (int sm = 0; sm < 4; sm++){
    #pragma unroll
    for (int r = 0; r < 4; r++){
      const int row = i0 + sm * 16 + cr + r;
      const float qi = qn[row];
      float* dstrow = &Dq[(size_t)row * N_Q];
      #pragma unroll
      for (int sn = 0; sn < 4; sn++){
        const int col = j0 + sn * 16 + cc;
        float d2 = qi + qn[col] - 2.0f * acc[sm][sn][r];
        dstrow[col] = sqrtf(fmaxf(d2, 0.f));
      }
    }
  }
}

// ---- per-row 13 smallest (ties -> smaller index), row in registers (unchanged).
__global__ __launch_bounds__(256) void topk_kernel(
    const float* __restrict__ Dq, int* __restrict__ nbr,
    float* __restrict__ dnbr, float* __restrict__ sigma)
{
  const int i = blockIdx.x, t = threadIdx.x;
  const float* row = Dq + (size_t)i * N_Q;
  float r[16];
  #pragma unroll
  for (int u = 0; u < 16; u++) r[u] = row[t + u * 256];

  __shared__ float pvf[4];
  __shared__ int   pif[4];
  __shared__ int   bwi_s;

  for (int s = 0; s < KNN + 1; s++){
    float best = FLT_MAX; int bj = 0x7fffffff;
    #pragma unroll
    for (int u = 0; u < 16; u++){
      float v = r[u];
      if (v < best){ best = v; bj = t + u * 256; }
    }
    #pragma unroll
    for (int o = 32; o; o >>= 1){
      float ov = __shfl_xor(best, o, 64); int oj = __shfl_xor(bj, o, 64);
      if (ov < best || (ov == best && oj < bj)){ best = ov; bj = oj; }
    }
    if ((t & 63) == 0){ pvf[t >> 6] = best; pif[t >> 6] = bj; }
    __syncthreads();
    if (t == 0){
      float bv = pvf[0]; int bi2 = pif[0];
      #pragma unroll
      for (int w2 = 1; w2 < 4; w2++){
        float v2 = pvf[w2]; int i2 = pif[w2];
        if (v2 < bv || (v2 == bv && i2 < bi2)){ bv = v2; bi2 = i2; }
      }
      bwi_s = bi2;
      if (s >= 1){ nbr[i*KNN + s - 1] = bi2; dnbr[i*KNN + s - 1] = bv; }
      if (s == KNN) sigma[i] = bv + 1e-8f;
    }
    __syncthreads();
    const int widx = bwi_s;
    if ((widx & 255) == t) r[widx >> 8] = FLT_MAX;
  }
}

// ============ hierarchical monotonic grid barrier (setup phases only) ============
__device__ __forceinline__ void gbar_leader(int* garr, int* gcnt, int* gen, int target){
  const int g = blockIdx.x >> 4;
  int old = __hip_atomic_fetch_add(&garr[g * 32], 1, __ATOMIC_RELAXED, __HIP_MEMORY_SCOPE_AGENT);
  if ((old & 15) == 15){
    int o2 = __hip_atomic_fetch_add(gcnt, 1, __ATOMIC_RELAXED, __HIP_MEMORY_SCOPE_AGENT);
    if ((o2 & 15) == 15)
      __hip_atomic_fetch_add(gen, 1, __ATOMIC_RELAXED, __HIP_MEMORY_SCOPE_AGENT);
  }
  while (__hip_atomic_load(gen, __ATOMIC_RELAXED, __HIP_MEMORY_SCOPE_AGENT) < target)
    __builtin_amdgcn_s_sleep(1);
}

// ============ packed {phase, delta} flag barrier — contiguous 8B slots ============
__device__ __forceinline__ void pbar_wave0(
    unsigned long long* pslot, int ph, int* sdm, float* sdelta_sh, int lane)
{
  const int par = ph & 1;
  unsigned long long* base = pslot + (size_t)par * NBLK;
  if (lane == 0){
    int myd = sdm[par]; sdm[par] = 0;
    unsigned long long pack =
        ((unsigned long long)(unsigned int)myd << 32) | (unsigned int)ph;
    __builtin_amdgcn_s_waitcnt(0);          // all prior y stores drained
    astore64(&base[blockIdx.x], pack);
  }
  int mx;
  while (1){
    unsigned long long v0 = aload64(&base[lane      ]);
    unsigned long long v1 = aload64(&base[lane +  64]);
    unsigned long long v2 = aload64(&base[lane + 128]);
    unsigned long long v3 = aload64(&base[lane + 192]);
    int f0 = (int)(unsigned int)v0, f1 = (int)(unsigned int)v1;
    int f2 = (int)(unsigned int)v2, f3 = (int)(unsigned int)v3;
    int mn = f0 < f1 ? f0 : f1;
    mn = f2 < mn ? f2 : mn;
    mn = f3 < mn ? f3 : mn;
    if (__all(mn >= ph)){
      int d0 = (int)(v0 >> 32), d1 = (int)(v1 >> 32);
      int d2 = (int)(v2 >> 32), d3 = (int)(v3 >> 32);
      mx = d0 > d1 ? d0 : d1;
      mx = d2 > mx ? d2 : mx;
      mx = d3 > mx ? d3 : mx;
      break;
    }
    __builtin_amdgcn_s_sleep(1);
  }
  #pragma unroll
  for (int o = 32; o; o >>= 1){ int ox = __shfl_xor(mx, o, 64); mx = ox > mx ? ox : mx; }
  if (lane == 0) *sdelta_sh = __int_as_float(mx);
}

// ---- chunked SpMV (R17): K groups of 8 edges, all loads issue concurrently,
//      then the fma sequence runs in the exact old order.
template<int K>
__device__ __forceinline__ void chunk_fma(
    const float* __restrict__ src, const int2* adj, int gbase, int lane,
    float& s0, float& s1, float& s2, float& s3,
    float& s4, float& s5, float& s6, float& s7)
{
  float yv[K][8], wv[K][8];
  #pragma unroll
  for (int g = 0; g < K; g++){
    #pragma unroll
    for (int u = 0; u < 8; u++){
      int2 a = adj[(gbase + g) * 8 + u];
      wv[g][u] = __int_as_float(a.y);
      yv[g][u] = aload(&src[a.x + lane]);
    }
  }
  #pragma unroll
  for (int g = 0; g < K; g++){
    s0 = fmaf(wv[g][0], yv[g][0], s0);
    s1 = fmaf(wv[g][1], yv[g][1], s1);
    s2 = fmaf(wv[g][2], yv[g][2], s2);
    s3 = fmaf(wv[g][3], yv[g][3], s3);
    s4 = fmaf(wv[g][4], yv[g][4], s4);
    s5 = fmaf(wv[g][5], yv[g][5], s5);
    s6 = fmaf(wv[g][6], yv[g][6], s6);
    s7 = fmaf(wv[g][7], yv[g][7], s7);
  }
}

__device__ __forceinline__ float spmv_row(
    const float* __restrict__ src, const int2* adj,
    const int* __restrict__ colA, const float* __restrict__ wA,
    int p0, int p1v, int lane)
{
  const int deg  = p1v - p0;
  const int ncap = deg < ADJ_CAP ? deg : ADJ_CAP;
  const int nfull = ncap & ~7;
  const int ng = nfull >> 3;
  float s0=0.f,s1=0.f,s2=0.f,s3=0.f,s4=0.f,s5=0.f,s6=0.f,s7=0.f;

  int g = 0;
  #pragma unroll 1
  for (; g + 4 <= ng; g += 4){
    chunk_fma<4>(src, adj, g, lane, s0,s1,s2,s3,s4,s5,s6,s7);
  }
  {
    const int left = ng - g;
    if (left == 3)      chunk_fma<3>(src, adj, g, lane, s0,s1,s2,s3,s4,s5,s6,s7);
    else if (left == 2) chunk_fma<2>(src, adj, g, lane, s0,s1,s2,s3,s4,s5,s6,s7);
    else if (left == 1) chunk_fma<1>(src, adj, g, lane, s0,s1,s2,s3,s4,s5,s6,s7);
  }

  if (deg > ADJ_CAP){
    int qg = p0 + ADJ_CAP;
    for (; qg + 8 <= p1v; qg += 8){
      s0 = fmaf(wA[qg    ], aload(&src[colA[qg    ] + lane]), s0);
      s1 = fmaf(wA[qg + 1], aload(&src[colA[qg + 1] + lane]), s1);
      s2 = fmaf(wA[qg + 2], aload(&src[colA[qg + 2] + lane]), s2);
      s3 = fmaf(wA[qg + 3], aload(&src[colA[qg + 3] + lane]), s3);
      s4 = fmaf(wA[qg + 4], aload(&src[colA[qg + 4] + lane]), s4);
      s5 = fmaf(wA[qg + 5], aload(&src[colA[qg + 5] + lane]), s5);
      s6 = fmaf(wA[qg + 6], aload(&src[colA[qg + 6] + lane]), s6);
      s7 = fmaf(wA[qg + 7], aload(&src[colA[qg + 7] + lane]), s7);
    }
    for (; qg < p1v; qg++)
      s0 = fmaf(wA[qg], aload(&src[colA[qg] + lane]), s0);
  } else {
    const int rem = deg - nfull;            // 0..7
    if (rem > 0){
      float yr[7], wr[7];
      #pragma unroll
      for (int u = 0; u < 7; u++){
        if (u < rem){
          int2 a = adj[nfull + u];
          wr[u] = __int_as_float(a.y);
          yr[u] = aload(&src[a.x + lane]);
        }
      }
      #pragma unroll
      for (int u = 0; u < 7; u++)
        if (u < rem) s0 = fmaf(wr[u], yr[u], s0);
    }
  }
  return ((s0+s1)+(s2+s3)) + ((s4+s5)+(s6+s7));
}

// ---- fused tail: EXACT revert to R17 (best measured: 262 us). Lockstep
//      pbar loop; chunked-MLP SpMV; agent-scope y-gather; no per-iter fences.
__global__ __launch_bounds__(1024, 4) void tail_loop(
    const float* __restrict__ Xq, const float* __restrict__ Pt,
    const float* __restrict__ pn, const float* __restrict__ qn,
    const int* __restrict__ nbr, const float* __restrict__ dnbr,
    const float* __restrict__ sigma,
    float* d2min, float* denom, float* wh,
    float* rowsum, int* indeg, int* rowptr, int* fillc,
    int* colA, float* wA, float* buf0, float* buf1,
    unsigned long long* pslot,
    int* gcnt, int* gen, int* garr, int* __restrict__ out)
{
  __shared__ int   sdm[2];
  __shared__ float sdelta;
  __shared__ union {
    float pchunk[CHK * N_C];                // 64 KB, P0a staging
    struct {
      int   ipart[1024];
      int   hist[1024];
      float cand[4096];
      int   candn, b1s, b2s;
    } s;
  } U;
  __shared__ int2  adjL[16 * ADJ_CAP];      // 12 KB, per-wave adjacency

  const int tid  = threadIdx.x;
  const int lane = tid & 63;
  const int wv   = tid >> 6;
  const int row  = blockIdx.x * 16 + wv;
  if (tid == 0){ sdm[0] = 0; sdm[1] = 0; }

  // ---------- P0a: a-row via LDS-staged Pt chunks (bit-exact dp order) ----------
  const float* xr = Xq + (size_t)row * DIM;
  const f4*    xr4 = (const f4*)xr;
  float dp[8];
  #pragma unroll
  for (int u = 0; u < 8; u++) dp[u] = 0.f;

  for (int f0 = 0; f0 < DIM; f0 += CHK){
    // cooperative stage: CHK*64 floats = 4096 f4; 1024 threads x 4 f4
    const f4* srcv = (const f4*)(Pt + (size_t)f0 * N_C);
    f4* dstv = (f4*)U.pchunk;
    #pragma unroll
    for (int u = 0; u < 4; u++) dstv[tid + u * 1024] = srcv[tid + u * 1024];
    __syncthreads();
    #pragma unroll 1
    for (int f = 0; f < CHK; f += 8){
      const f4 xa = xr4[(f0 + f) >> 2];
      const f4 xb = xr4[((f0 + f) >> 2) + 1];
      const float* pc = U.pchunk + f * N_C + lane;
      dp[0] = fmaf(xa[0], pc[0      ], dp[0]);
      dp[1] = fmaf(xa[1], pc[N_C    ], dp[1]);
      dp[2] = fmaf(xa[2], pc[N_C * 2], dp[2]);
      dp[3] = fmaf(xa[3], pc[N_C * 3], dp[3]);
      dp[4] = fmaf(xb[0], pc[N_C * 4], dp[4]);
      dp[5] = fmaf(xb[1], pc[N_C * 5], dp[5]);
      dp[6] = fmaf(xb[2], pc[N_C * 6], dp[6]);
      dp[7] = fmaf(xb[3], pc[N_C * 7], dp[7]);
    }
    __syncthreads();                        // before next chunk overwrite
  }
  const float dot = ((dp[0]+dp[1])+(dp[2]+dp[3])) + ((dp[4]+dp[5])+(dp[6]+dp[7]));
  const float av  = fmaxf(qn[row] + pn[lane] - 2.0f * dot, 0.0f);
  const float d2m = wave_min64(av);
  if (lane == 0) astore(&d2min[row], d2m);

  // ---------- P0b: edge weights + degrees ----------
  const int e = blockIdx.x * 1024 + tid;
  if (e < N_Q * KNN){
    const int i = e / KNN;
    const int j = nbr[e];
    float wgt = 0.5f * expf(-dnbr[e] / (sigma[i] * sigma[j]));
    astore(&wh[e], wgt);
    atomicAdd(&rowsum[i], wgt);
    atomicAdd(&rowsum[j], wgt);
    atomicAdd(&indeg[j], 1);
  }

  __syncthreads();
  if (tid == 0) gbar_leader(garr, gcnt, gen, 1);
  __syncthreads();

  // ---------- P1: y0 + scan (block 0) + median (block 1) ----------
  float xv = -av;
  float m = wave_max64(xv), ee = expf(xv - m), ss = wave_sum64(ee);
  float prev = ee / ss;                    // y0
  astore(&buf0[row * N_C + lane], prev);

  if (blockIdx.x == 0){
    int* ipart = U.s.ipart;
    const int base = tid * 4;
    int c0 = aloadi(&indeg[base]),     c1 = aloadi(&indeg[base + 1]);
    int c2 = aloadi(&indeg[base + 2]), c3 = aloadi(&indeg[base + 3]);
    const int s4 = c0 + c1 + c2 + c3;
    ipart[tid] = s4;
    __syncthreads();
    for (int off = 1; off < 1024; off <<= 1){
      int v = (tid >= off) ? ipart[tid - off] : 0;
      __syncthreads();
      ipart[tid] += v;
      __syncthreads();
    }
    int run = ipart[tid] - s4;
    astorei(&rowptr[base    ], KNN * (base    ) + run); run += c0;
    astorei(&rowptr[base + 1], KNN * (base + 1) + run); run += c1;
    astorei(&rowptr[base + 2], KNN * (base + 2) + run); run += c2;
    astorei(&rowptr[base + 3], KNN * (base + 3) + run);
    if (tid == 1023) astorei(&rowptr[N_Q], KNN * N_Q + ipart[1023]);
  }
  if (blockIdx.x == 1){
    int*   hist = U.s.hist;
    float* cand = U.s.cand;
    const int base = tid * 4;
    float dv[4];
    #pragma unroll
    for (int u = 0; u < 4; u++) dv[u] = sqrtf(aload(&d2min[base + u]));
    float mn = fminf(fminf(dv[0], dv[1]), fminf(dv[2], dv[3]));
    float mx = fmaxf(fmaxf(dv[0], dv[1]), fmaxf(dv[2], dv[3]));
    mn = wave_min64(mn); mx = wave_max64(mx);
    if (lane == 0){ cand[wv] = mn; cand[wv + 16] = mx; }
    __syncthreads();
    if (tid == 0){
      float a = cand[0], b = cand[16];
      for (int k = 1; k < 16; k++){ a = fminf(a, cand[k]); b = fmaxf(b, cand[16 + k]); }
      cand[32] = a; cand[33] = b;
    }
    __syncthreads();
    mn = cand[32]; mx = cand[33];
    const float rng = mx - mn;
    const float scale = (rng > 0.f) ? (1024.0f / rng) : 0.f;
    hist[tid] = 0;
    __syncthreads();
    int bidx[4];
    #pragma unroll
    for (int u = 0; u < 4; u++){
      int b = (int)((dv[u] - mn) * scale);
      b = b < 0 ? 0 : (b > 1023 ? 1023 : b);
      bidx[u] = b;
      atomicAdd(&hist[b], 1);
    }
    __syncthreads();
    for (int off = 1; off < 1024; off <<= 1){
      int v = (tid >= off) ? hist[tid - off] : 0;
      __syncthreads();
      hist[tid] += v;
      __syncthreads();
    }
    if (hist[tid] >= 2048 && (tid == 0 || hist[tid - 1] < 2048)) U.s.b1s = tid;
    if (hist[tid] >= 2049 && (tid == 0 || hist[tid - 1] < 2049)) U.s.b2s = tid;
    if (tid == 0) U.s.candn = 0;
    __syncthreads();
    const int b1 = U.s.b1s, b2 = U.s.b2s;
    const int cntBefore = (b1 > 0) ? hist[b1 - 1] : 0;
    #pragma unroll
    for (int u = 0; u < 4; u++){
      if (bidx[u] >= b1 && bidx[u] <= b2){
        int pos = atomicAdd(&U.s.candn, 1);
        cand[pos] = dv[u];
      }
    }
    __syncthreads();
    const int mcnt = U.s.candn;
    int P = 2; while (P < mcnt) P <<= 1;
    for (int i2 = mcnt + tid; i2 < P; i2 += 1024) cand[i2] = FLT_MAX;
    __syncthreads();
    for (int k = 2; k <= P; k <<= 1){
      for (int st = k >> 1; st > 0; st >>= 1){
        for (int i2 = tid; i2 < P; i2 += 1024){
          int j2 = i2 ^ st;
          if (j2 > i2){
            float a2 = cand[i2], b3 = cand[j2];
            bool up = ((i2 & k) == 0);
            if (up ? (a2 > b3) : (a2 < b3)){ cand[i2] = b3; cand[j2] = a2; }
          }
        }
        __syncthreads();
      }
    }
    if (tid == 0){
      float v1 = cand[2047 - cntBefore], v2 = cand[2048 - cntBefore];
      float med = 0.5f * (v1 + v2);
      astore(denom, 2.0f * med * med + 1e-8f);
    }
  }

  __syncthreads();
  if (tid == 0) gbar_leader(garr, gcnt, gen, 2);
  __syncthreads();

  // ---------- P2: CSR fill + per-row coef ----------
  if (e < N_Q * KNN){
    const int i = e / KNN, tt = e % KNN;
    const int j = nbr[e];
    const float wgt = aload(&wh[e]);
    const int p = aloadi(&rowptr[i]) + tt;
    colA[p] = j * N_C; wA[p] = wgt;
    const int q = aloadi(&rowptr[j]) + KNN + atomicAdd(&fillc[j], 1);
    colA[q] = i * N_C; wA[q] = wgt;
  }
  const float cf = expf(-d2m / aload(denom)) / (aload(&rowsum[row]) + 1e-8f);
  const int p0  = aloadi(&rowptr[row]);
  const int p1v = aloadi(&rowptr[row + 1]);

  __builtin_amdgcn_fence(__ATOMIC_RELEASE, "agent");
  __syncthreads();
  if (tid == 0) gbar_leader(garr, gcnt, gen, 3);
  __syncthreads();
  __builtin_amdgcn_fence(__ATOMIC_ACQUIRE, "agent");

  // ---------- preload loop-invariant adjacency into LDS ----------
  {
    const int deg  = p1v - p0;
    const int ncap = deg < ADJ_CAP ? deg : ADJ_CAP;
    for (int u = lane; u < ncap; u += 64)
      adjL[wv * ADJ_CAP + u] = make_int2(colA[p0 + u], __float_as_int(wA[p0 + u]));
  }
  __syncthreads();
  const int2* adj = adjL + wv * ADJ_CAP;

  // ---------- P3: y1 = step(y0); publish delta via pbar phase 1 ----------
  float cur;
  {
    float sum = spmv_row(buf0, adj, colA, wA, p0, p1v, lane);
    float xv2 = -av + cf * sum;
    float mm = wave_max64(xv2), e2 = expf(xv2 - mm), ss2 = wave_sum64(e2);
    cur = e2 / ss2;
    astore(&buf1[row * N_C + lane], cur);
  }
  float dm = wave_max64(fabsf(cur - prev));
  if (lane == 0) atomicMax(&sdm[1], __float_as_int(dm));
  __syncthreads();                         // drains all waves' y stores + LDS
  if (wv == 0) pbar_wave0(pslot, 1, sdm, &sdelta, lane);
  __syncthreads();
  float delta = sdelta;

  // ---------- P4: the while-loop ----------
  int par = 1;                             // buffer currently holding y_new
  for (int t = 0;; t++){
    if (t >= MAX_ITER || delta < EPS_CONV) break;
    const float* src = par ? buf1 : buf0;
    float*       dst = par ? buf0 : buf1;
    float sum = spmv_row(src, adj, colA, wA, p0, p1v, lane);
    float xv2 = -av + cf * sum;
    float mm = wave_max64(xv2), e2 = expf(xv2 - mm), ss2 = wave_sum64(e2);
    float nxt = e2 / ss2;
    astore(&dst[row * N_C + lane], nxt);
    const int ph = t + 2;
    dm = wave_max64(fabsf(nxt - cur));
    if (lane == 0) atomicMax(&sdm[ph & 1], __float_as_int(dm));
    __syncthreads();
    if (wv == 0) pbar_wave0(pslot, ph, sdm, &sdelta, lane);
    __syncthreads();
    delta = sdelta;
    prev = cur; cur = nxt; par ^= 1;
  }

  // argmax of y (prev); first occurrence on ties
  float bv = prev; int bi = lane;
  #pragma unroll
  for (int o = 32; o; o >>= 1){
    float ov = __shfl_xor(bv, o, 64); int oi = __shfl_xor(bi, o, 64);
    if (ov > bv || (ov == bv && oi < bi)){ bv = ov; bi = oi; }
  }
  if (lane == 0) out[row] = bi;
}

extern "C" void kernel_launch(void* const* d_in, const int* in_sizes, int n_in,
                              void* d_out, int out_size, void* d_ws, size_t ws_size,
                              hipStream_t stream)
{
  const float* feat_s = (const float*)d_in[0];
  const int*   y_s    = (const int*)d_in[1];
  const float* feat_q = (const float*)d_in[2];
  int* out = (int*)d_out;

  char* wp = (char*)d_ws;
  auto alloc = [&](size_t bytes) -> char* {
    char* p = wp;
    wp += (bytes + 255) & ~(size_t)255;
    return p;
  };
  float*     Dq  = (float*)alloc((size_t)N_Q * N_Q * 4);     // 64 MB
  _Float16*  Xh  = (_Float16*)alloc((size_t)N_Q * DIM * 2);  // 8 MB
  _Float16*  Xl  = (_Float16*)alloc((size_t)N_Q * DIM * 2);  // 8 MB
  float* Pt     = (float*)alloc((size_t)DIM * N_C * 4);
  float* pn     = (float*)alloc(N_C * 4);
  float* qn     = (float*)alloc(N_Q * 4);
  float* d2min  = (float*)alloc(N_Q * 4);
  float* denom  = (float*)alloc(256);
  int*   nbr    = (int*)alloc((size_t)N_Q * KNN * 4);
  float* dnbr   = (float*)alloc((size_t)N_Q * KNN * 4);
  float* sigma  = (float*)alloc(N_Q * 4);
  float* wh     = (float*)alloc((size_t)N_Q * KNN * 4);
  int*   rowptr = (int*)alloc((N_Q + 1) * 4);
  int*   colA   = (int*)alloc((size_t)2 * N_Q * KNN * 4);
  float* wA     = (float*)alloc((size_t)2 * N_Q * KNN * 4);
  float* buf0   = (float*)alloc((size_t)N_Q * N_C * 4);
  float* buf1   = (float*)alloc((size_t)N_Q * N_C * 4);
  // zero-region: rowsum | indeg | fillc | syncw | garr | pslot (packed, 4KB)
  const size_t zbytes = (size_t)N_Q*12 + 256 + 2048 + 2 * NBLK * 8;
  char*  zbase  = alloc(zbytes);
  float* rowsum = (float*)(zbase);
  int*   indeg  = (int*)(zbase + N_Q*4);
  int*   fillc  = (int*)(zbase + N_Q*8);
  int*   syncw  = (int*)(zbase + N_Q*12);
  int*   garr   = (int*)(zbase + N_Q*12 + 256);
  unsigned long long* pslot = (unsigned long long*)(zbase + N_Q*12 + 256 + 2048);

  hipMemsetAsync(zbase, 0, zbytes, stream);

  proto_kernel <<<N_C, 256, 0, stream>>>(feat_s, y_s, Pt, pn);
  prep_kernel  <<<N_Q, 256, 0, stream>>>(feat_q, qn, Xh, Xl);
  dist_mfma    <<<dim3(N_Q/128, N_Q/128), 256, 0, stream>>>(Xh, Xl, qn, Dq);
  topk_kernel  <<<N_Q, 256, 0, stream>>>(Dq, nbr, dnbr, sigma);

  int* gcnt = &syncw[0];
  int* gen  = &syncw[32];
  const float* Xq = feat_q;
  void* args[] = {&Xq, &Pt, &pn, &qn, &nbr, &dnbr, &sigma,
                  &d2min, &denom, &wh, &rowsum, &indeg, &rowptr, &fillc,
                  &colA, &wA, &buf0, &buf1, &pslot,
                  &gcnt, &gen, &garr, &out};
  hipLaunchCooperativeKernel((void*)tail_loop, dim3(NBLK), dim3(1024), args, 0, stream);
}

// Round 8
// 472.570 us; speedup vs baseline: 38.7234x; 1.0079x over previous
//
#include <hip/hip_runtime.h>
#include <hip/hip_cooperative_groups.h>
#include <cfloat>
#include <cmath>

#define N_Q 4096
#define N_S 1600
#define DIM 1024
#define N_C 64
#define KNN 12
#define MAX_ITER 50
#define EPS_CONV 1e-4f
#define NBLK 256         // tail_loop grid size
#define ADJ_CAP 96       // per-row LDS adjacency capacity (multiple of 8)
#define CHK 256          // P0a: Pt features staged per LDS chunk
#define DPAD 40          // dist_mfma LDS k-stride (f16): 32 + 8 pad -> ~2-way banks

typedef _Float16 h8 __attribute__((ext_vector_type(8)));
typedef float    f4 __attribute__((ext_vector_type(4)));

__device__ __forceinline__ float wave_max64(float v){
  #pragma unroll
  for (int o = 32; o; o >>= 1) v = fmaxf(v, __shfl_xor(v, o, 64));
  return v;
}
__device__ __forceinline__ float wave_sum64(float v){
  #pragma unroll
  for (int o = 32; o; o >>= 1) v += __shfl_xor(v, o, 64);
  return v;
}
__device__ __forceinline__ float wave_min64(float v){
  #pragma unroll
  for (int o = 32; o; o >>= 1) v = fminf(v, __shfl_xor(v, o, 64));
  return v;
}

// coherent (device-visible) element accesses for cross-block-communicated data
__device__ __forceinline__ float aload(const float* p){
  return __hip_atomic_load(p, __ATOMIC_RELAXED, __HIP_MEMORY_SCOPE_AGENT);
}
__device__ __forceinline__ void astore(float* p, float v){
  __hip_atomic_store(p, v, __ATOMIC_RELAXED, __HIP_MEMORY_SCOPE_AGENT);
}
__device__ __forceinline__ int aloadi(const int* p){
  return __hip_atomic_load(p, __ATOMIC_RELAXED, __HIP_MEMORY_SCOPE_AGENT);
}
__device__ __forceinline__ void astorei(int* p, int v){
  __hip_atomic_store(p, v, __ATOMIC_RELAXED, __HIP_MEMORY_SCOPE_AGENT);
}
__device__ __forceinline__ unsigned long long aload64(const unsigned long long* p){
  return __hip_atomic_load(p, __ATOMIC_RELAXED, __HIP_MEMORY_SCOPE_AGENT);
}
__device__ __forceinline__ void astore64(unsigned long long* p, unsigned long long v){
  __hip_atomic_store(p, v, __ATOMIC_RELAXED, __HIP_MEMORY_SCOPE_AGENT);
}

// ---- R21: fused setup kernel. Blocks 0..63 run the (verbatim) proto body;
//      blocks 64..4159 run the (verbatim) prep body. Proto blocks dispatch
//      FIRST so their serial per-class accumulation overlaps prep instead of
//      running as a separate serialized launch. Branch is block-uniform ->
//      __syncthreads inside each branch is legal. Zero numeric change.
__global__ __launch_bounds__(256) void setup_kernel(
    const float* __restrict__ fs, const int* __restrict__ ys,
    float* __restrict__ Pt, float* __restrict__ pn,
    const float* __restrict__ X, float* __restrict__ qn,
    _Float16* __restrict__ Xh, _Float16* __restrict__ Xl)
{
  __shared__ union {
    struct {                                // proto branch
      int   list[N_S];
      int   pref[256];
      int   lcount;
      float red[256];
    } p;
    float red[256];                         // prep branch
  } S;

  const int t = threadIdx.x;

  if (blockIdx.x < N_C){
    // ================= proto (verbatim R13 body) =================
    const int c = blockIdx.x;
    int loc[7]; int cnt = 0;
    const int base = t * 7;                  // 256*7 = 1792 >= 1600
    #pragma unroll
    for (int u = 0; u < 7; u++){
      const int i = base + u;
      if (i < N_S && ys[i] == c) loc[cnt++] = i;
    }
    S.p.pref[t] = cnt;
    __syncthreads();
    for (int off = 1; off < 256; off <<= 1){
      int v = (t >= off) ? S.p.pref[t - off] : 0;
      __syncthreads();
      S.p.pref[t] += v;
      __syncthreads();
    }
    const int start = S.p.pref[t] - cnt;
    for (int u = 0; u < cnt; u++) S.p.list[start + u] = loc[u];
    if (t == 255) S.p.lcount = S.p.pref[255];
    __syncthreads();

    const int n = S.p.lcount;
    float a0 = 0.f, a1 = 0.f, a2 = 0.f, a3 = 0.f;
    for (int m = 0; m < n; m++){
      const float* r = fs + (size_t)S.p.list[m] * DIM;
      a0 += r[t]; a1 += r[t + 256]; a2 += r[t + 512]; a3 += r[t + 768];
    }
    const float inv = 1.0f / fmaxf((float)n, 1.0f);
    const float v0 = a0*inv, v1 = a1*inv, v2 = a2*inv, v3 = a3*inv;
    Pt[(t      )*N_C + c] = v0;
    Pt[(t + 256)*N_C + c] = v1;
    Pt[(t + 512)*N_C + c] = v2;
    Pt[(t + 768)*N_C + c] = v3;
    S.p.red[t] = v0*v0 + v1*v1 + v2*v2 + v3*v3;
    __syncthreads();
    for (int o = 128; o; o >>= 1){ if (t < o) S.p.red[t] += S.p.red[t + o]; __syncthreads(); }
    if (t == 0) pn[c] = S.p.red[0];
  } else {
    // ================= prep (verbatim body) =================
    const int i = blockIdx.x - N_C;
    const float* r = X + (size_t)i * DIM;
    const float v0 = r[t], v1 = r[t+256], v2 = r[t+512], v3 = r[t+768];
    const size_t b = (size_t)i * DIM;
    _Float16 h0 = (_Float16)v0, h1 = (_Float16)v1, h2 = (_Float16)v2, h3 = (_Float16)v3;
    Xh[b + t      ] = h0; Xl[b + t      ] = (_Float16)(v0 - (float)h0);
    Xh[b + t + 256] = h1; Xl[b + t + 256] = (_Float16)(v1 - (float)h1);
    Xh[b + t + 512] = h2; Xl[b + t + 512] = (_Float16)(v2 - (float)h2);
    Xh[b + t + 768] = h3; Xl[b + t + 768] = (_Float16)(v3 - (float)h3);
    S.red[t] = v0*v0 + v1*v1 + v2*v2 + v3*v3;
    __syncthreads();
    for (int o = 128; o; o >>= 1){ if (t < o) S.red[t] += S.red[t + o]; __syncthreads(); }
    if (t == 0) qn[i] = S.red[0];
  }
}

// ---- pairwise distances via f16 split-precision MFMA (R20 LDS staging,
//      unchanged; Dq bit-identical; XCD swizzle kept).
__global__ __launch_bounds__(256, 3) void dist_mfma(
    const _Float16* __restrict__ Xh, const _Float16* __restrict__ Xl,
    const float* __restrict__ qn, float* __restrict__ Dq)
{
  __shared__ __align__(16) _Float16 As[2][128][DPAD];  // [hi/lo][row][k] 20KB
  __shared__ __align__(16) _Float16 Bs[2][128][DPAD];  // 20KB

  const int t = threadIdx.x, w = t >> 6, l = t & 63;
  const int lb  = blockIdx.y * 32 + blockIdx.x;   // dispatch-linear id
  const int xcd = lb & 7, k = lb >> 3;            // round-robin XCD map
  const int bxs = xcd * 4 + (k >> 5);             // 4 col-blocks per XCD
  const int bys = k & 31;
  const int bi0 = bys * 128, bj0 = bxs * 128;
  const int i0w = (w >> 1) * 64;                  // wave sub-tile in block
  const int j0w = (w & 1) * 64;
  const int fr = l & 15;
  const int kq = (l >> 4) * 8;

  // staging: thread t covers row (t>>1), 32B segment (t&1)
  const int srow = t >> 1;
  const int sseg = (t & 1) * 16;                  // f16 offset within row

  f4 acc[4][4];
  #pragma unroll
  for (int a = 0; a < 4; a++)
    #pragma unroll
    for (int b = 0; b < 4; b++) acc[a][b] = (f4){0.f, 0.f, 0.f, 0.f};

  const size_t abase = (size_t)(bi0 + srow) * DIM + sseg;
  const size_t bbase = (size_t)(bj0 + srow) * DIM + sseg;

  #pragma unroll 1
  for (int k0 = 0; k0 < DIM; k0 += 32){
    // issue all 8 staging loads before the barrier (in flight during wait)
    h8 va0 = *(const h8*)(Xh + abase + k0);
    h8 va1 = *(const h8*)(Xh + abase + k0 + 8);
    h8 vb0 = *(const h8*)(Xl + abase + k0);
    h8 vb1 = *(const h8*)(Xl + abase + k0 + 8);
    h8 vc0 = *(const h8*)(Xh + bbase + k0);
    h8 vc1 = *(const h8*)(Xh + bbase + k0 + 8);
    h8 vd0 = *(const h8*)(Xl + bbase + k0);
    h8 vd1 = *(const h8*)(Xl + bbase + k0 + 8);
    __syncthreads();                      // prev iter's LDS reads complete
    *(h8*)&As[0][srow][sseg    ] = va0;
    *(h8*)&As[0][srow][sseg + 8] = va1;
    *(h8*)&As[1][srow][sseg    ] = vb0;
    *(h8*)&As[1][srow][sseg + 8] = vb1;
    *(h8*)&Bs[0][srow][sseg    ] = vc0;
    *(h8*)&Bs[0][srow][sseg + 8] = vc1;
    *(h8*)&Bs[1][srow][sseg    ] = vd0;
    *(h8*)&Bs[1][srow][sseg + 8] = vd1;
    __syncthreads();                      // tiles ready

    h8 ah[4], al[4];
    #pragma unroll
    for (int sm = 0; sm < 4; sm++){
      ah[sm] = *(const h8*)&As[0][i0w + sm * 16 + fr][kq];
      al[sm] = *(const h8*)&As[1][i0w + sm * 16 + fr][kq];
    }
    #pragma unroll
    for (int sn = 0; sn < 4; sn++){
      h8 bh = *(const h8*)&Bs[0][j0w + sn * 16 + fr][kq];
      h8 bl = *(const h8*)&Bs[1][j0w + sn * 16 + fr][kq];
      #pragma unroll
      for (int sm = 0; sm < 4; sm++){
        acc[sm][sn] = __builtin_amdgcn_mfma_f32_16x16x32_f16(ah[sm], bh, acc[sm][sn], 0, 0, 0);
        acc[sm][sn] = __builtin_amdgcn_mfma_f32_16x16x32_f16(ah[sm], bl, acc[sm][sn], 0, 0, 0);
        acc[sm][sn] = __builtin_amdgcn_mfma_f32_16x16x32_f16(al[sm], bh, acc[sm][sn], 0, 0, 0);
      }
    }
  }

  const int i0 = bi0 + i0w;
  const int j0 = bj0 + j0w;
  const int cr = (l >> 4) * 4;
  const int cc = l & 15;
  #pragma unroll
  for (int sm = 0; sm < 4; sm++){
    #pragma unroll
    for (int r = 0; r < 4; r++){
      const int row = i0 + sm * 16 + cr + r;
      const float qi = qn[row];
      float* dstrow = &Dq[(size_t)row * N_Q];
      #pragma unroll
      for (int sn = 0; sn < 4; sn++){
        const int col = j0 + sn * 16 + cc;
        float d2 = qi + qn[col] - 2.0f * acc[sm][sn][r];
        dstrow[col] = sqrtf(fmaxf(d2, 0.f));
      }
    }
  }
}

// ---- per-row 13 smallest (ties -> smaller index).
//      R21: wave-local selection + single merge. Each of the 4 waves finds
//      its own top-13 of its 1024 elements with shfl-only rounds (no block
//      barriers; was 26 __syncthreads + 13 serial thread-0 merges). Then one
//      __syncthreads and wave 0 merges the 52 candidates in 13 shfl rounds.
//      Pure comparisons, same (value, smaller-index) order; the global s-th
//      smallest equals the s-th smallest of the union of per-wave top-13s
//      -> nbr/dnbr/sigma bit-identical.
__global__ __launch_bounds__(256) void topk_kernel(
    const float* __restrict__ Dq, int* __restrict__ nbr,
    float* __restrict__ dnbr, float* __restrict__ sigma)
{
  const int i = blockIdx.x, t = threadIdx.x;
  const int lane = t & 63, w = t >> 6;
  const float* row = Dq + (size_t)i * N_Q;
  float r[16];
  #pragma unroll
  for (int u = 0; u < 16; u++) r[u] = row[t + u * 256];

  __shared__ float cvf[4 * (KNN + 1)];
  __shared__ int   cif[4 * (KNN + 1)];

  // ---- wave-local top-13 (winner of round s parked on lane s) ----
  float keepv = FLT_MAX; int keepi = 0x7fffffff;
  for (int s = 0; s < KNN + 1; s++){
    float best = FLT_MAX; int bj = 0x7fffffff;
    #pragma unroll
    for (int u = 0; u < 16; u++){
      float v = r[u];
      if (v < best){ best = v; bj = t + u * 256; }   // first hit = min index
    }
    #pragma unroll
    for (int o = 32; o; o >>= 1){
      float ov = __shfl_xor(best, o, 64); int oj = __shfl_xor(bj, o, 64);
      if (ov < best || (ov == best && oj < bj)){ best = ov; bj = oj; }
    }
    if (lane == s){ keepv = best; keepi = bj; }
    if ((bj & 255) == t) r[bj >> 8] = FLT_MAX;       // owner consumes
  }
  if (lane < KNN + 1){ cvf[w * (KNN + 1) + lane] = keepv; cif[w * (KNN + 1) + lane] = keepi; }
  __syncthreads();

  // ---- wave 0: merge 52 candidates, 13 selection rounds ----
  if (w == 0){
    float mv = FLT_MAX; int mi = 0x7fffffff;
    if (lane < 4 * (KNN + 1)){ mv = cvf[lane]; mi = cif[lane]; }
    for (int s = 0; s < KNN + 1; s++){
      float best = mv; int bj = mi;
      #pragma unroll
      for (int o = 32; o; o >>= 1){
        float ov = __shfl_xor(best, o, 64); int oj = __shfl_xor(bj, o, 64);
        if (ov < best || (ov == best && oj < bj)){ best = ov; bj = oj; }
      }
      if (lane == 0){
        if (s >= 1){ nbr[i*KNN + s - 1] = bj; dnbr[i*KNN + s - 1] = best; }
        if (s == KNN) sigma[i] = best + 1e-8f;
      }
      if (mi == bj) mv = FLT_MAX;                    // consume (indices unique)
    }
  }
}

// ============ hierarchical monotonic grid barrier (setup phases only) ============
__device__ __forceinline__ void gbar_leader(int* garr, int* gcnt, int* gen, int target){
  const int g = blockIdx.x >> 4;
  int old = __hip_atomic_fetch_add(&garr[g * 32], 1, __ATOMIC_RELAXED, __HIP_MEMORY_SCOPE_AGENT);
  if ((old & 15) == 15){
    int o2 = __hip_atomic_fetch_add(gcnt, 1, __ATOMIC_RELAXED, __HIP_MEMORY_SCOPE_AGENT);
    if ((o2 & 15) == 15)
      __hip_atomic_fetch_add(gen, 1, __ATOMIC_RELAXED, __HIP_MEMORY_SCOPE_AGENT);
  }
  while (__hip_atomic_load(gen, __ATOMIC_RELAXED, __HIP_MEMORY_SCOPE_AGENT) < target)
    __builtin_amdgcn_s_sleep(1);
}

// ============ packed {phase, delta} flag barrier — contiguous 8B slots ============
__device__ __forceinline__ void pbar_wave0(
    unsigned long long* pslot, int ph, int* sdm, float* sdelta_sh, int lane)
{
  const int par = ph & 1;
  unsigned long long* base = pslot + (size_t)par * NBLK;
  if (lane == 0){
    int myd = sdm[par]; sdm[par] = 0;
    unsigned long long pack =
        ((unsigned long long)(unsigned int)myd << 32) | (unsigned int)ph;
    __builtin_amdgcn_s_waitcnt(0);          // all prior y stores drained
    astore64(&base[blockIdx.x], pack);
  }
  int mx;
  while (1){
    unsigned long long v0 = aload64(&base[lane      ]);
    unsigned long long v1 = aload64(&base[lane +  64]);
    unsigned long long v2 = aload64(&base[lane + 128]);
    unsigned long long v3 = aload64(&base[lane + 192]);
    int f0 = (int)(unsigned int)v0, f1 = (int)(unsigned int)v1;
    int f2 = (int)(unsigned int)v2, f3 = (int)(unsigned int)v3;
    int mn = f0 < f1 ? f0 : f1;
    mn = f2 < mn ? f2 : mn;
    mn = f3 < mn ? f3 : mn;
    if (__all(mn >= ph)){
      int d0 = (int)(v0 >> 32), d1 = (int)(v1 >> 32);
      int d2 = (int)(v2 >> 32), d3 = (int)(v3 >> 32);
      mx = d0 > d1 ? d0 : d1;
      mx = d2 > mx ? d2 : mx;
      mx = d3 > mx ? d3 : mx;
      break;
    }
    __builtin_amdgcn_s_sleep(1);
  }
  #pragma unroll
  for (int o = 32; o; o >>= 1){ int ox = __shfl_xor(mx, o, 64); mx = ox > mx ? ox : mx; }
  if (lane == 0) *sdelta_sh = __int_as_float(mx);
}

// ---- chunked SpMV (R17): K groups of 8 edges, all loads issue concurrently,
//      then the fma sequence runs in the exact old order.
template<int K>
__device__ __forceinline__ void chunk_fma(
    const float* __restrict__ src, const int2* adj, int gbase, int lane,
    float& s0, float& s1, float& s2, float& s3,
    float& s4, float& s5, float& s6, float& s7)
{
  float yv[K][8], wv[K][8];
  #pragma unroll
  for (int g = 0; g < K; g++){
    #pragma unroll
    for (int u = 0; u < 8; u++){
      int2 a = adj[(gbase + g) * 8 + u];
      wv[g][u] = __int_as_float(a.y);
      yv[g][u] = aload(&src[a.x + lane]);
    }
  }
  #pragma unroll
  for (int g = 0; g < K; g++){
    s0 = fmaf(wv[g][0], yv[g][0], s0);
    s1 = fmaf(wv[g][1], yv[g][1], s1);
    s2 = fmaf(wv[g][2], yv[g][2], s2);
    s3 = fmaf(wv[g][3], yv[g][3], s3);
    s4 = fmaf(wv[g][4], yv[g][4], s4);
    s5 = fmaf(wv[g][5], yv[g][5], s5);
    s6 = fmaf(wv[g][6], yv[g][6], s6);
    s7 = fmaf(wv[g][7], yv[g][7], s7);
  }
}

__device__ __forceinline__ float spmv_row(
    const float* __restrict__ src, const int2* adj,
    const int* __restrict__ colA, const float* __restrict__ wA,
    int p0, int p1v, int lane)
{
  const int deg  = p1v - p0;
  const int ncap = deg < ADJ_CAP ? deg : ADJ_CAP;
  const int nfull = ncap & ~7;
  const int ng = nfull >> 3;
  float s0=0.f,s1=0.f,s2=0.f,s3=0.f,s4=0.f,s5=0.f,s6=0.f,s7=0.f;

  int g = 0;
  #pragma unroll 1
  for (; g + 4 <= ng; g += 4){
    chunk_fma<4>(src, adj, g, lane, s0,s1,s2,s3,s4,s5,s6,s7);
  }
  {
    const int left = ng - g;
    if (left == 3)      chunk_fma<3>(src, adj, g, lane, s0,s1,s2,s3,s4,s5,s6,s7);
    else if (left == 2) chunk_fma<2>(src, adj, g, lane, s0,s1,s2,s3,s4,s5,s6,s7);
    else if (left == 1) chunk_fma<1>(src, adj, g, lane, s0,s1,s2,s3,s4,s5,s6,s7);
  }

  if (deg > ADJ_CAP){
    int qg = p0 + ADJ_CAP;
    for (; qg + 8 <= p1v; qg += 8){
      s0 = fmaf(wA[qg    ], aload(&src[colA[qg    ] + lane]), s0);
      s1 = fmaf(wA[qg + 1], aload(&src[colA[qg + 1] + lane]), s1);
      s2 = fmaf(wA[qg + 2], aload(&src[colA[qg + 2] + lane]), s2);
      s3 = fmaf(wA[qg + 3], aload(&src[colA[qg + 3] + lane]), s3);
      s4 = fmaf(wA[qg + 4], aload(&src[colA[qg + 4] + lane]), s4);
      s5 = fmaf(wA[qg + 5], aload(&src[colA[qg + 5] + lane]), s5);
      s6 = fmaf(wA[qg + 6], aload(&src[colA[qg + 6] + lane]), s6);
      s7 = fmaf(wA[qg + 7], aload(&src[colA[qg + 7] + lane]), s7);
    }
    for (; qg < p1v; qg++)
      s0 = fmaf(wA[qg], aload(&src[colA[qg] + lane]), s0);
  } else {
    const int rem = deg - nfull;            // 0..7
    if (rem > 0){
      float yr[7], wr[7];
      #pragma unroll
      for (int u = 0; u < 7; u++){
        if (u < rem){
          int2 a = adj[nfull + u];
          wr[u] = __int_as_float(a.y);
          yr[u] = aload(&src[a.x + lane]);
        }
      }
      #pragma unroll
      for (int u = 0; u < 7; u++)
        if (u < rem) s0 = fmaf(wr[u], yr[u], s0);
    }
  }
  return ((s0+s1)+(s2+s3)) + ((s4+s5)+(s6+s7));
}

// ---- fused tail: EXACT R17 structure (best measured: 262 us). Lockstep
//      pbar loop; chunked-MLP SpMV; agent-scope y-gather; no per-iter fences.
__global__ __launch_bounds__(1024, 4) void tail_loop(
    const float* __restrict__ Xq, const float* __restrict__ Pt,
    const float* __restrict__ pn, const float* __restrict__ qn,
    const int* __restrict__ nbr, const float* __restrict__ dnbr,
    const float* __restrict__ sigma,
    float* d2min, float* denom, float* wh,
    float* rowsum, int* indeg, int* rowptr, int* fillc,
    int* colA, float* wA, float* buf0, float* buf1,
    unsigned long long* pslot,
    int* gcnt, int* gen, int* garr, int* __restrict__ out)
{
  __shared__ int   sdm[2];
  __shared__ float sdelta;
  __shared__ union {
    float pchunk[CHK * N_C];                // 64 KB, P0a staging
    struct {
      int   ipart[1024];
      int   hist[1024];
      float cand[4096];
      int   candn, b1s, b2s;
    } s;
  } U;
  __shared__ int2  adjL[16 * ADJ_CAP];      // 12 KB, per-wave adjacency

  const int tid  = threadIdx.x;
  const int lane = tid & 63;
  const int wv   = tid >> 6;
  const int row  = blockIdx.x * 16 + wv;
  if (tid == 0){ sdm[0] = 0; sdm[1] = 0; }

  // ---------- P0a: a-row via LDS-staged Pt chunks (bit-exact dp order) ----------
  const float* xr = Xq + (size_t)row * DIM;
  const f4*    xr4 = (const f4*)xr;
  float dp[8];
  #pragma unroll
  for (int u = 0; u < 8; u++) dp[u] = 0.f;

  for (int f0 = 0; f0 < DIM; f0 += CHK){
    // cooperative stage: CHK*64 floats = 4096 f4; 1024 threads x 4 f4
    const f4* srcv = (const f4*)(Pt + (size_t)f0 * N_C);
    f4* dstv = (f4*)U.pchunk;
    #pragma unroll
    for (int u = 0; u < 4; u++) dstv[tid + u * 1024] = srcv[tid + u * 1024];
    __syncthreads();
    #pragma unroll 1
    for (int f = 0; f < CHK; f += 8){
      const f4 xa = xr4[(f0 + f) >> 2];
      const f4 xb = xr4[((f0 + f) >> 2) + 1];
      const float* pc = U.pchunk + f * N_C + lane;
      dp[0] = fmaf(xa[0], pc[0      ], dp[0]);
      dp[1] = fmaf(xa[1], pc[N_C    ], dp[1]);
      dp[2] = fmaf(xa[2], pc[N_C * 2], dp[2]);
      dp[3] = fmaf(xa[3], pc[N_C * 3], dp[3]);
      dp[4] = fmaf(xb[0], pc[N_C * 4], dp[4]);
      dp[5] = fmaf(xb[1], pc[N_C * 5], dp[5]);
      dp[6] = fmaf(xb[2], pc[N_C * 6], dp[6]);
      dp[7] = fmaf(xb[3], pc[N_C * 7], dp[7]);
    }
    __syncthreads();                        // before next chunk overwrite
  }
  const float dot = ((dp[0]+dp[1])+(dp[2]+dp[3])) + ((dp[4]+dp[5])+(dp[6]+dp[7]));
  const float av  = fmaxf(qn[row] + pn[lane] - 2.0f * dot, 0.0f);
  const float d2m = wave_min64(av);
  if (lane == 0) astore(&d2min[row], d2m);

  // ---------- P0b: edge weights + degrees ----------
  const int e = blockIdx.x * 1024 + tid;
  if (e < N_Q * KNN){
    const int i = e / KNN;
    const int j = nbr[e];
    float wgt = 0.5f * expf(-dnbr[e] / (sigma[i] * sigma[j]));
    astore(&wh[e], wgt);
    atomicAdd(&rowsum[i], wgt);
    atomicAdd(&rowsum[j], wgt);
    atomicAdd(&indeg[j], 1);
  }

  __syncthreads();
  if (tid == 0) gbar_leader(garr, gcnt, gen, 1);
  __syncthreads();

  // ---------- P1: y0 + scan (block 0) + median (block 1) ----------
  float xv = -av;
  float m = wave_max64(xv), ee = expf(xv - m), ss = wave_sum64(ee);
  float prev = ee / ss;                    // y0
  astore(&buf0[row * N_C + lane], prev);

  if (blockIdx.x == 0){
    int* ipart = U.s.ipart;
    const int base = tid * 4;
    int c0 = aloadi(&indeg[base]),     c1 = aloadi(&indeg[base + 1]);
    int c2 = aloadi(&indeg[base + 2]), c3 = aloadi(&indeg[base + 3]);
    const int s4 = c0 + c1 + c2 + c3;
    ipart[tid] = s4;
    __syncthreads();
    for (int off = 1; off < 1024; off <<= 1){
      int v = (tid >= off) ? ipart[tid - off] : 0;
      __syncthreads();
      ipart[tid] += v;
      __syncthreads();
    }
    int run = ipart[tid] - s4;
    astorei(&rowptr[base    ], KNN * (base    ) + run); run += c0;
    astorei(&rowptr[base + 1], KNN * (base + 1) + run); run += c1;
    astorei(&rowptr[base + 2], KNN * (base + 2) + run); run += c2;
    astorei(&rowptr[base + 3], KNN * (base + 3) + run);
    if (tid == 1023) astorei(&rowptr[N_Q], KNN * N_Q + ipart[1023]);
  }
  if (blockIdx.x == 1){
    int*   hist = U.s.hist;
    float* cand = U.s.cand;
    const int base = tid * 4;
    float dv[4];
    #pragma unroll
    for (int u = 0; u < 4; u++) dv[u] = sqrtf(aload(&d2min[base + u]));
    float mn = fminf(fminf(dv[0], dv[1]), fminf(dv[2], dv[3]));
    float mx = fmaxf(fmaxf(dv[0], dv[1]), fmaxf(dv[2], dv[3]));
    mn = wave_min64(mn); mx = wave_max64(mx);
    if (lane == 0){ cand[wv] = mn; cand[wv + 16] = mx; }
    __syncthreads();
    if (tid == 0){
      float a = cand[0], b = cand[16];
      for (int k = 1; k < 16; k++){ a = fminf(a, cand[k]); b = fmaxf(b, cand[16 + k]); }
      cand[32] = a; cand[33] = b;
    }
    __syncthreads();
    mn = cand[32]; mx = cand[33];
    const float rng = mx - mn;
    const float scale = (rng > 0.f) ? (1024.0f / rng) : 0.f;
    hist[tid] = 0;
    __syncthreads();
    int bidx[4];
    #pragma unroll
    for (int u = 0; u < 4; u++){
      int b = (int)((dv[u] - mn) * scale);
      b = b < 0 ? 0 : (b > 1023 ? 1023 : b);
      bidx[u] = b;
      atomicAdd(&hist[b], 1);
    }
    __syncthreads();
    for (int off = 1; off < 1024; off <<= 1){
      int v = (tid >= off) ? hist[tid - off] : 0;
      __syncthreads();
      hist[tid] += v;
      __syncthreads();
    }
    if (hist[tid] >= 2048 && (tid == 0 || hist[tid - 1] < 2048)) U.s.b1s = tid;
    if (hist[tid] >= 2049 && (tid == 0 || hist[tid - 1] < 2049)) U.s.b2s = tid;
    if (tid == 0) U.s.candn = 0;
    __syncthreads();
    const int b1 = U.s.b1s, b2 = U.s.b2s;
    const int cntBefore = (b1 > 0) ? hist[b1 - 1] : 0;
    #pragma unroll
    for (int u = 0; u < 4; u++){
      if (bidx[u] >= b1 && bidx[u] <= b2){
        int pos = atomicAdd(&U.s.candn, 1);
        cand[pos] = dv[u];
      }
    }
    __syncthreads();
    const int mcnt = U.s.candn;
    int P = 2; while (P < mcnt) P <<= 1;
    for (int i2 = mcnt + tid; i2 < P; i2 += 1024) cand[i2] = FLT_MAX;
    __syncthreads();
    for (int k = 2; k <= P; k <<= 1){
      for (int st = k >> 1; st > 0; st >>= 1){
        for (int i2 = tid; i2 < P; i2 += 1024){
          int j2 = i2 ^ st;
          if (j2 > i2){
            float a2 = cand[i2], b3 = cand[j2];
            bool up = ((i2 & k) == 0);
            if (up ? (a2 > b3) : (a2 < b3)){ cand[i2] = b3; cand[j2] = a2; }
          }
        }
        __syncthreads();
      }
    }
    if (tid == 0){
      float v1 = cand[2047 - cntBefore], v2 = cand[2048 - cntBefore];
      float med = 0.5f * (v1 + v2);
      astore(denom, 2.0f * med * med + 1e-8f);
    }
  }

  __syncthreads();
  if (tid == 0) gbar_leader(garr, gcnt, gen, 2);
  __syncthreads();

  // ---------- P2: CSR fill + per-row coef ----------
  if (e < N_Q * KNN){
    const int i = e / KNN, tt = e % KNN;
    const int j = nbr[e];
    const float wgt = aload(&wh[e]);
    const int p = aloadi(&rowptr[i]) + tt;
    colA[p] = j * N_C; wA[p] = wgt;
    const int q = aloadi(&rowptr[j]) + KNN + atomicAdd(&fillc[j], 1);
    colA[q] = i * N_C; wA[q] = wgt;
  }
  const float cf = expf(-d2m / aload(denom)) / (aload(&rowsum[row]) + 1e-8f);
  const int p0  = aloadi(&rowptr[row]);
  const int p1v = aloadi(&rowptr[row + 1]);

  __builtin_amdgcn_fence(__ATOMIC_RELEASE, "agent");
  __syncthreads();
  if (tid == 0) gbar_leader(garr, gcnt, gen, 3);
  __syncthreads();
  __builtin_amdgcn_fence(__ATOMIC_ACQUIRE, "agent");

  // ---------- preload loop-invariant adjacency into LDS ----------
  {
    const int deg  = p1v - p0;
    const int ncap = deg < ADJ_CAP ? deg : ADJ_CAP;
    for (int u = lane; u < ncap; u += 64)
      adjL[wv * ADJ_CAP + u] = make_int2(colA[p0 + u], __float_as_int(wA[p0 + u]));
  }
  __syncthreads();
  const int2* adj = adjL + wv * ADJ_CAP;

  // ---------- P3: y1 = step(y0); publish delta via pbar phase 1 ----------
  float cur;
  {
    float sum = spmv_row(buf0, adj, colA, wA, p0, p1v, lane);
    float xv2 = -av + cf * sum;
    float mm = wave_max64(xv2), e2 = expf(xv2 - mm), ss2 = wave_sum64(e2);
    cur = e2 / ss2;
    astore(&buf1[row * N_C + lane], cur);
  }
  float dm = wave_max64(fabsf(cur - prev));
  if (lane == 0) atomicMax(&sdm[1], __float_as_int(dm));
  __syncthreads();                         // drains all waves' y stores + LDS
  if (wv == 0) pbar_wave0(pslot, 1, sdm, &sdelta, lane);
  __syncthreads();
  float delta = sdelta;

  // ---------- P4: the while-loop ----------
  int par = 1;                             // buffer currently holding y_new
  for (int t = 0;; t++){
    if (t >= MAX_ITER || delta < EPS_CONV) break;
    const float* src = par ? buf1 : buf0;
    float*       dst = par ? buf0 : buf1;
    float sum = spmv_row(src, adj, colA, wA, p0, p1v, lane);
    float xv2 = -av + cf * sum;
    float mm = wave_max64(xv2), e2 = expf(xv2 - mm), ss2 = wave_sum64(e2);
    float nxt = e2 / ss2;
    astore(&dst[row * N_C + lane], nxt);
    const int ph = t + 2;
    dm = wave_max64(fabsf(nxt - cur));
    if (lane == 0) atomicMax(&sdm[ph & 1], __float_as_int(dm));
    __syncthreads();
    if (wv == 0) pbar_wave0(pslot, ph, sdm, &sdelta, lane);
    __syncthreads();
    delta = sdelta;
    prev = cur; cur = nxt; par ^= 1;
  }

  // argmax of y (prev); first occurrence on ties
  float bv = prev; int bi = lane;
  #pragma unroll
  for (int o = 32; o; o >>= 1){
    float ov = __shfl_xor(bv, o, 64); int oi = __shfl_xor(bi, o, 64);
    if (ov > bv || (ov == bv && oi < bi)){ bv = ov; bi = oi; }
  }
  if (lane == 0) out[row] = bi;
}

extern "C" void kernel_launch(void* const* d_in, const int* in_sizes, int n_in,
                              void* d_out, int out_size, void* d_ws, size_t ws_size,
                              hipStream_t stream)
{
  const float* feat_s = (const float*)d_in[0];
  const int*   y_s    = (const int*)d_in[1];
  const float* feat_q = (const float*)d_in[2];
  int* out = (int*)d_out;

  char* wp = (char*)d_ws;
  auto alloc = [&](size_t bytes) -> char* {
    char* p = wp;
    wp += (bytes + 255) & ~(size_t)255;
    return p;
  };
  float*     Dq  = (float*)alloc((size_t)N_Q * N_Q * 4);     // 64 MB
  _Float16*  Xh  = (_Float16*)alloc((size_t)N_Q * DIM * 2);  // 8 MB
  _Float16*  Xl  = (_Float16*)alloc((size_t)N_Q * DIM * 2);  // 8 MB
  float* Pt     = (float*)alloc((size_t)DIM * N_C * 4);
  float* pn     = (float*)alloc(N_C * 4);
  float* qn     = (float*)alloc(N_Q * 4);
  float* d2min  = (float*)alloc(N_Q * 4);
  float* denom  = (float*)alloc(256);
  int*   nbr    = (int*)alloc((size_t)N_Q * KNN * 4);
  float* dnbr   = (float*)alloc((size_t)N_Q * KNN * 4);
  float* sigma  = (float*)alloc(N_Q * 4);
  float* wh     = (float*)alloc((size_t)N_Q * KNN * 4);
  int*   rowptr = (int*)alloc((N_Q + 1) * 4);
  int*   colA   = (int*)alloc((size_t)2 * N_Q * KNN * 4);
  float* wA     = (float*)alloc((size_t)2 * N_Q * KNN * 4);
  float* buf0   = (float*)alloc((size_t)N_Q * N_C * 4);
  float* buf1   = (float*)alloc((size_t)N_Q * N_C * 4);
  // zero-region: rowsum | indeg | fillc | syncw | garr | pslot (packed, 4KB)
  const size_t zbytes = (size_t)N_Q*12 + 256 + 2048 + 2 * NBLK * 8;
  char*  zbase  = alloc(zbytes);
  float* rowsum = (float*)(zbase);
  int*   indeg  = (int*)(zbase + N_Q*4);
  int*   fillc  = (int*)(zbase + N_Q*8);
  int*   syncw  = (int*)(zbase + N_Q*12);
  int*   garr   = (int*)(zbase + N_Q*12 + 256);
  unsigned long long* pslot = (unsigned long long*)(zbase + N_Q*12 + 256 + 2048);

  hipMemsetAsync(zbase, 0, zbytes, stream);

  setup_kernel <<<N_Q + N_C, 256, 0, stream>>>(feat_s, y_s, Pt, pn, feat_q, qn, Xh, Xl);
  dist_mfma    <<<dim3(N_Q/128, N_Q/128), 256, 0, stream>>>(Xh, Xl, qn, Dq);
  topk_kernel  <<<N_Q, 256, 0, stream>>>(Dq, nbr, dnbr, sigma);

  int* gcnt = &syncw[0];
  int* gen  = &syncw[32];
  const float* Xq = feat_q;
  void* args[] = {&Xq, &Pt, &pn, &qn, &nbr, &dnbr, &sigma,
                  &d2min, &denom, &wh, &rowsum, &indeg, &rowptr, &fillc,
                  &colA, &wA, &buf0, &buf1, &pslot,
                  &gcnt, &gen, &garr, &out};
  hipLaunchCooperativeKernel((void*)tail_loop, dim3(NBLK), dim3(1024), args, 0, stream);
}

// Round 9
// 454.245 us; speedup vs baseline: 40.2856x; 1.0403x over previous
//
#include <hip/hip_runtime.h>
#include <hip/hip_cooperative_groups.h>
#include <cfloat>
#include <cmath>

#define N_Q 4096
#define N_S 1600
#define DIM 1024
#define N_C 64
#define KNN 12
#define MAX_ITER 50
#define EPS_CONV 1e-4f
#define NBLK 256         // tail_loop grid size
#define ADJ_CAP 96       // per-row LDS adjacency capacity (multiple of 8)
#define CHK 256          // P0a: Pt features staged per LDS chunk
#define DPAD 40          // dist_mfma LDS k-stride (f16): 32 + 8 pad -> ~2-way banks

typedef _Float16 h8 __attribute__((ext_vector_type(8)));
typedef float    f4 __attribute__((ext_vector_type(4)));

__device__ __forceinline__ float wave_max64(float v){
  #pragma unroll
  for (int o = 32; o; o >>= 1) v = fmaxf(v, __shfl_xor(v, o, 64));
  return v;
}
__device__ __forceinline__ float wave_sum64(float v){
  #pragma unroll
  for (int o = 32; o; o >>= 1) v += __shfl_xor(v, o, 64);
  return v;
}
__device__ __forceinline__ float wave_min64(float v){
  #pragma unroll
  for (int o = 32; o; o >>= 1) v = fminf(v, __shfl_xor(v, o, 64));
  return v;
}

// coherent (device-visible) element accesses for cross-block-communicated data
__device__ __forceinline__ float aload(const float* p){
  return __hip_atomic_load(p, __ATOMIC_RELAXED, __HIP_MEMORY_SCOPE_AGENT);
}
__device__ __forceinline__ void astore(float* p, float v){
  __hip_atomic_store(p, v, __ATOMIC_RELAXED, __HIP_MEMORY_SCOPE_AGENT);
}
__device__ __forceinline__ int aloadi(const int* p){
  return __hip_atomic_load(p, __ATOMIC_RELAXED, __HIP_MEMORY_SCOPE_AGENT);
}
__device__ __forceinline__ void astorei(int* p, int v){
  __hip_atomic_store(p, v, __ATOMIC_RELAXED, __HIP_MEMORY_SCOPE_AGENT);
}
__device__ __forceinline__ unsigned long long aload64(const unsigned long long* p){
  return __hip_atomic_load(p, __ATOMIC_RELAXED, __HIP_MEMORY_SCOPE_AGENT);
}
__device__ __forceinline__ void astore64(unsigned long long* p, unsigned long long v){
  __hip_atomic_store(p, v, __ATOMIC_RELAXED, __HIP_MEMORY_SCOPE_AGENT);
}

// ---- R21 fused setup kernel (unchanged): blocks 0..63 proto, 64..4159 prep.
__global__ __launch_bounds__(256) void setup_kernel(
    const float* __restrict__ fs, const int* __restrict__ ys,
    float* __restrict__ Pt, float* __restrict__ pn,
    const float* __restrict__ X, float* __restrict__ qn,
    _Float16* __restrict__ Xh, _Float16* __restrict__ Xl)
{
  __shared__ union {
    struct {                                // proto branch
      int   list[N_S];
      int   pref[256];
      int   lcount;
      float red[256];
    } p;
    float red[256];                         // prep branch
  } S;

  const int t = threadIdx.x;

  if (blockIdx.x < N_C){
    // ================= proto =================
    const int c = blockIdx.x;
    int loc[7]; int cnt = 0;
    const int base = t * 7;                  // 256*7 = 1792 >= 1600
    #pragma unroll
    for (int u = 0; u < 7; u++){
      const int i = base + u;
      if (i < N_S && ys[i] == c) loc[cnt++] = i;
    }
    S.p.pref[t] = cnt;
    __syncthreads();
    for (int off = 1; off < 256; off <<= 1){
      int v = (t >= off) ? S.p.pref[t - off] : 0;
      __syncthreads();
      S.p.pref[t] += v;
      __syncthreads();
    }
    const int start = S.p.pref[t] - cnt;
    for (int u = 0; u < cnt; u++) S.p.list[start + u] = loc[u];
    if (t == 255) S.p.lcount = S.p.pref[255];
    __syncthreads();

    const int n = S.p.lcount;
    float a0 = 0.f, a1 = 0.f, a2 = 0.f, a3 = 0.f;
    for (int m = 0; m < n; m++){
      const float* r = fs + (size_t)S.p.list[m] * DIM;
      a0 += r[t]; a1 += r[t + 256]; a2 += r[t + 512]; a3 += r[t + 768];
    }
    const float inv = 1.0f / fmaxf((float)n, 1.0f);
    const float v0 = a0*inv, v1 = a1*inv, v2 = a2*inv, v3 = a3*inv;
    Pt[(t      )*N_C + c] = v0;
    Pt[(t + 256)*N_C + c] = v1;
    Pt[(t + 512)*N_C + c] = v2;
    Pt[(t + 768)*N_C + c] = v3;
    S.p.red[t] = v0*v0 + v1*v1 + v2*v2 + v3*v3;
    __syncthreads();
    for (int o = 128; o; o >>= 1){ if (t < o) S.p.red[t] += S.p.red[t + o]; __syncthreads(); }
    if (t == 0) pn[c] = S.p.red[0];
  } else {
    // ================= prep =================
    const int i = blockIdx.x - N_C;
    const float* r = X + (size_t)i * DIM;
    const float v0 = r[t], v1 = r[t+256], v2 = r[t+512], v3 = r[t+768];
    const size_t b = (size_t)i * DIM;
    _Float16 h0 = (_Float16)v0, h1 = (_Float16)v1, h2 = (_Float16)v2, h3 = (_Float16)v3;
    Xh[b + t      ] = h0; Xl[b + t      ] = (_Float16)(v0 - (float)h0);
    Xh[b + t + 256] = h1; Xl[b + t + 256] = (_Float16)(v1 - (float)h1);
    Xh[b + t + 512] = h2; Xl[b + t + 512] = (_Float16)(v2 - (float)h2);
    Xh[b + t + 768] = h3; Xl[b + t + 768] = (_Float16)(v3 - (float)h3);
    S.red[t] = v0*v0 + v1*v1 + v2*v2 + v3*v3;
    __syncthreads();
    for (int o = 128; o; o >>= 1){ if (t < o) S.red[t] += S.red[t + o]; __syncthreads(); }
    if (t == 0) qn[i] = S.red[0];
  }
}

// ---- pairwise distances via f16 split-precision MFMA.
//      R22: 128x256 block tile, sm=8/sn=4 per wave (was 128x128, sm=4/sn=4).
//      MFMA:LDS-read ratio 96:24 (was 48:16) and 25% less staging traffic
//      per output. LDS 60KB -> 2 blocks/CU. Per-output MFMA sequence is
//      UNCHANGED (k0 ascending, hh/hl/lh pass order, fr/kq lane mapping;
//      operands are staged copies) -> Dq bit-identical.
__global__ __launch_bounds__(256, 2) void dist_mfma(
    const _Float16* __restrict__ Xh, const _Float16* __restrict__ Xl,
    const float* __restrict__ qn, float* __restrict__ Dq)
{
  __shared__ __align__(16) _Float16 As[2][128][DPAD];  // 20 KB
  __shared__ __align__(16) _Float16 Bs[2][256][DPAD];  // 40 KB

  const int t = threadIdx.x, w = t >> 6, l = t & 63;
  const int lb  = blockIdx.x;              // 512 blocks
  const int xcd = lb & 7, k = lb >> 3;     // round-robin XCD map, k in [0,64)
  const int bxs = xcd * 2 + (k >> 5);      // [0,16) col-panels of 256
  const int bys = k & 31;                  // [0,32) row-panels of 128
  const int bi0 = bys * 128, bj0 = bxs * 256;
  const int j0w = w * 64;                  // wave's 64-col slice
  const int fr = l & 15;
  const int kq = (l >> 4) * 8;

  // staging A: thread t covers row (t>>1), 16-f16 segment (t&1)
  const int arow = t >> 1;
  const int aseg = (t & 1) * 16;
  // staging B: thread t covers row t, all 32 f16 of the k-slab
  const int brow = t;

  f4 acc[8][4];
  #pragma unroll
  for (int a = 0; a < 8; a++)
    #pragma unroll
    for (int b = 0; b < 4; b++) acc[a][b] = (f4){0.f, 0.f, 0.f, 0.f};

  const size_t abase = (size_t)(bi0 + arow) * DIM + aseg;
  const size_t bbase = (size_t)(bj0 + brow) * DIM;

  #pragma unroll 1
  for (int k0 = 0; k0 < DIM; k0 += 32){
    // issue all 12 staging loads before the barrier (in flight during wait)
    h8 va0 = *(const h8*)(Xh + abase + k0);
    h8 va1 = *(const h8*)(Xh + abase + k0 + 8);
    h8 vb0 = *(const h8*)(Xl + abase + k0);
    h8 vb1 = *(const h8*)(Xl + abase + k0 + 8);
    h8 vc0 = *(const h8*)(Xh + bbase + k0);
    h8 vc1 = *(const h8*)(Xh + bbase + k0 + 8);
    h8 vc2 = *(const h8*)(Xh + bbase + k0 + 16);
    h8 vc3 = *(const h8*)(Xh + bbase + k0 + 24);
    h8 vd0 = *(const h8*)(Xl + bbase + k0);
    h8 vd1 = *(const h8*)(Xl + bbase + k0 + 8);
    h8 vd2 = *(const h8*)(Xl + bbase + k0 + 16);
    h8 vd3 = *(const h8*)(Xl + bbase + k0 + 24);
    __syncthreads();                      // prev iter's LDS reads complete
    *(h8*)&As[0][arow][aseg    ] = va0;
    *(h8*)&As[0][arow][aseg + 8] = va1;
    *(h8*)&As[1][arow][aseg    ] = vb0;
    *(h8*)&As[1][arow][aseg + 8] = vb1;
    *(h8*)&Bs[0][brow][0 ] = vc0;
    *(h8*)&Bs[0][brow][8 ] = vc1;
    *(h8*)&Bs[0][brow][16] = vc2;
    *(h8*)&Bs[0][brow][24] = vc3;
    *(h8*)&Bs[1][brow][0 ] = vd0;
    *(h8*)&Bs[1][brow][8 ] = vd1;
    *(h8*)&Bs[1][brow][16] = vd2;
    *(h8*)&Bs[1][brow][24] = vd3;
    __syncthreads();                      // tiles ready

    h8 ah[8], al[8];
    #pragma unroll
    for (int sm = 0; sm < 8; sm++){
      ah[sm] = *(const h8*)&As[0][sm * 16 + fr][kq];
      al[sm] = *(const h8*)&As[1][sm * 16 + fr][kq];
    }
    #pragma unroll
    for (int sn = 0; sn < 4; sn++){
      h8 bh = *(const h8*)&Bs[0][j0w + sn * 16 + fr][kq];
      h8 bl = *(const h8*)&Bs[1][j0w + sn * 16 + fr][kq];
      #pragma unroll
      for (int sm = 0; sm < 8; sm++){
        acc[sm][sn] = __builtin_amdgcn_mfma_f32_16x16x32_f16(ah[sm], bh, acc[sm][sn], 0, 0, 0);
        acc[sm][sn] = __builtin_amdgcn_mfma_f32_16x16x32_f16(ah[sm], bl, acc[sm][sn], 0, 0, 0);
        acc[sm][sn] = __builtin_amdgcn_mfma_f32_16x16x32_f16(al[sm], bh, acc[sm][sn], 0, 0, 0);
      }
    }
  }

  const int cr = (l >> 4) * 4;
  const int cc = l & 15;
  #pragma unroll
  for (int sm = 0; sm < 8; sm++){
    #pragma unroll
    for (int r = 0; r < 4; r++){
      const int row = bi0 + sm * 16 + cr + r;
      const float qi = qn[row];
      float* dstrow = &Dq[(size_t)row * N_Q];
      #pragma unroll
      for (int sn = 0; sn < 4; sn++){
        const int col = bj0 + j0w + sn * 16 + cc;
        float d2 = qi + qn[col] - 2.0f * acc[sm][sn][r];
        dstrow[col] = sqrtf(fmaxf(d2, 0.f));
      }
    }
  }
}

// ---- per-row 13 smallest (R21 wave-local + merge, unchanged).
__global__ __launch_bounds__(256) void topk_kernel(
    const float* __restrict__ Dq, int* __restrict__ nbr,
    float* __restrict__ dnbr, float* __restrict__ sigma)
{
  const int i = blockIdx.x, t = threadIdx.x;
  const int lane = t & 63, w = t >> 6;
  const float* row = Dq + (size_t)i * N_Q;
  float r[16];
  #pragma unroll
  for (int u = 0; u < 16; u++) r[u] = row[t + u * 256];

  __shared__ float cvf[4 * (KNN + 1)];
  __shared__ int   cif[4 * (KNN + 1)];

  // ---- wave-local top-13 (winner of round s parked on lane s) ----
  float keepv = FLT_MAX; int keepi = 0x7fffffff;
  for (int s = 0; s < KNN + 1; s++){
    float best = FLT_MAX; int bj = 0x7fffffff;
    #pragma unroll
    for (int u = 0; u < 16; u++){
      float v = r[u];
      if (v < best){ best = v; bj = t + u * 256; }   // first hit = min index
    }
    #pragma unroll
    for (int o = 32; o; o >>= 1){
      float ov = __shfl_xor(best, o, 64); int oj = __shfl_xor(bj, o, 64);
      if (ov < best || (ov == best && oj < bj)){ best = ov; bj = oj; }
    }
    if (lane == s){ keepv = best; keepi = bj; }
    if ((bj & 255) == t) r[bj >> 8] = FLT_MAX;       // owner consumes
  }
  if (lane < KNN + 1){ cvf[w * (KNN + 1) + lane] = keepv; cif[w * (KNN + 1) + lane] = keepi; }
  __syncthreads();

  // ---- wave 0: merge 52 candidates, 13 selection rounds ----
  if (w == 0){
    float mv = FLT_MAX; int mi = 0x7fffffff;
    if (lane < 4 * (KNN + 1)){ mv = cvf[lane]; mi = cif[lane]; }
    for (int s = 0; s < KNN + 1; s++){
      float best = mv; int bj = mi;
      #pragma unroll
      for (int o = 32; o; o >>= 1){
        float ov = __shfl_xor(best, o, 64); int oj = __shfl_xor(bj, o, 64);
        if (ov < best || (ov == best && oj < bj)){ best = ov; bj = oj; }
      }
      if (lane == 0){
        if (s >= 1){ nbr[i*KNN + s - 1] = bj; dnbr[i*KNN + s - 1] = best; }
        if (s == KNN) sigma[i] = best + 1e-8f;
      }
      if (mi == bj) mv = FLT_MAX;                    // consume (indices unique)
    }
  }
}

// ============ hierarchical monotonic grid barrier (setup phases only) ============
__device__ __forceinline__ void gbar_leader(int* garr, int* gcnt, int* gen, int target){
  const int g = blockIdx.x >> 4;
  int old = __hip_atomic_fetch_add(&garr[g * 32], 1, __ATOMIC_RELAXED, __HIP_MEMORY_SCOPE_AGENT);
  if ((old & 15) == 15){
    int o2 = __hip_atomic_fetch_add(gcnt, 1, __ATOMIC_RELAXED, __HIP_MEMORY_SCOPE_AGENT);
    if ((o2 & 15) == 15)
      __hip_atomic_fetch_add(gen, 1, __ATOMIC_RELAXED, __HIP_MEMORY_SCOPE_AGENT);
  }
  while (__hip_atomic_load(gen, __ATOMIC_RELAXED, __HIP_MEMORY_SCOPE_AGENT) < target)
    __builtin_amdgcn_s_sleep(1);
}

// ============ packed {phase, delta} flag barrier — contiguous 8B slots ============
__device__ __forceinline__ void pbar_wave0(
    unsigned long long* pslot, int ph, int* sdm, float* sdelta_sh, int lane)
{
  const int par = ph & 1;
  unsigned long long* base = pslot + (size_t)par * NBLK;
  if (lane == 0){
    int myd = sdm[par]; sdm[par] = 0;
    unsigned long long pack =
        ((unsigned long long)(unsigned int)myd << 32) | (unsigned int)ph;
    __builtin_amdgcn_s_waitcnt(0);          // all prior y stores drained
    astore64(&base[blockIdx.x], pack);
  }
  int mx;
  while (1){
    unsigned long long v0 = aload64(&base[lane      ]);
    unsigned long long v1 = aload64(&base[lane +  64]);
    unsigned long long v2 = aload64(&base[lane + 128]);
    unsigned long long v3 = aload64(&base[lane + 192]);
    int f0 = (int)(unsigned int)v0, f1 = (int)(unsigned int)v1;
    int f2 = (int)(unsigned int)v2, f3 = (int)(unsigned int)v3;
    int mn = f0 < f1 ? f0 : f1;
    mn = f2 < mn ? f2 : mn;
    mn = f3 < mn ? f3 : mn;
    if (__all(mn >= ph)){
      int d0 = (int)(v0 >> 32), d1 = (int)(v1 >> 32);
      int d2 = (int)(v2 >> 32), d3 = (int)(v3 >> 32);
      mx = d0 > d1 ? d0 : d1;
      mx = d2 > mx ? d2 : mx;
      mx = d3 > mx ? d3 : mx;
      break;
    }
    __builtin_amdgcn_s_sleep(1);
  }
  #pragma unroll
  for (int o = 32; o; o >>= 1){ int ox = __shfl_xor(mx, o, 64); mx = ox > mx ? ox : mx; }
  if (lane == 0) *sdelta_sh = __int_as_float(mx);
}

// ---- chunked SpMV (R17): K groups of 8 edges, all loads issue concurrently,
//      then the fma sequence runs in the exact old order.
template<int K>
__device__ __forceinline__ void chunk_fma(
    const float* __restrict__ src, const int2* adj, int gbase, int lane,
    float& s0, float& s1, float& s2, float& s3,
    float& s4, float& s5, float& s6, float& s7)
{
  float yv[K][8], wv[K][8];
  #pragma unroll
  for (int g = 0; g < K; g++){
    #pragma unroll
    for (int u = 0; u < 8; u++){
      int2 a = adj[(gbase + g) * 8 + u];
      wv[g][u] = __int_as_float(a.y);
      yv[g][u] = aload(&src[a.x + lane]);
    }
  }
  #pragma unroll
  for (int g = 0; g < K; g++){
    s0 = fmaf(wv[g][0], yv[g][0], s0);
    s1 = fmaf(wv[g][1], yv[g][1], s1);
    s2 = fmaf(wv[g][2], yv[g][2], s2);
    s3 = fmaf(wv[g][3], yv[g][3], s3);
    s4 = fmaf(wv[g][4], yv[g][4], s4);
    s5 = fmaf(wv[g][5], yv[g][5], s5);
    s6 = fmaf(wv[g][6], yv[g][6], s6);
    s7 = fmaf(wv[g][7], yv[g][7], s7);
  }
}

__device__ __forceinline__ float spmv_row(
    const float* __restrict__ src, const int2* adj,
    const int* __restrict__ colA, const float* __restrict__ wA,
    int p0, int p1v, int lane)
{
  const int deg  = p1v - p0;
  const int ncap = deg < ADJ_CAP ? deg : ADJ_CAP;
  const int nfull = ncap & ~7;
  const int ng = nfull >> 3;
  float s0=0.f,s1=0.f,s2=0.f,s3=0.f,s4=0.f,s5=0.f,s6=0.f,s7=0.f;

  int g = 0;
  #pragma unroll 1
  for (; g + 4 <= ng; g += 4){
    chunk_fma<4>(src, adj, g, lane, s0,s1,s2,s3,s4,s5,s6,s7);
  }
  {
    const int left = ng - g;
    if (left == 3)      chunk_fma<3>(src, adj, g, lane, s0,s1,s2,s3,s4,s5,s6,s7);
    else if (left == 2) chunk_fma<2>(src, adj, g, lane, s0,s1,s2,s3,s4,s5,s6,s7);
    else if (left == 1) chunk_fma<1>(src, adj, g, lane, s0,s1,s2,s3,s4,s5,s6,s7);
  }

  if (deg > ADJ_CAP){
    int qg = p0 + ADJ_CAP;
    for (; qg + 8 <= p1v; qg += 8){
      s0 = fmaf(wA[qg    ], aload(&src[colA[qg    ] + lane]), s0);
      s1 = fmaf(wA[qg + 1], aload(&src[colA[qg + 1] + lane]), s1);
      s2 = fmaf(wA[qg + 2], aload(&src[colA[qg + 2] + lane]), s2);
      s3 = fmaf(wA[qg + 3], aload(&src[colA[qg + 3] + lane]), s3);
      s4 = fmaf(wA[qg + 4], aload(&src[colA[qg + 4] + lane]), s4);
      s5 = fmaf(wA[qg + 5], aload(&src[colA[qg + 5] + lane]), s5);
      s6 = fmaf(wA[qg + 6], aload(&src[colA[qg + 6] + lane]), s6);
      s7 = fmaf(wA[qg + 7], aload(&src[colA[qg + 7] + lane]), s7);
    }
    for (; qg < p1v; qg++)
      s0 = fmaf(wA[qg], aload(&src[colA[qg] + lane]), s0);
  } else {
    const int rem = deg - nfull;            // 0..7
    if (rem > 0){
      float yr[7], wr[7];
      #pragma unroll
      for (int u = 0; u < 7; u++){
        if (u < rem){
          int2 a = adj[nfull + u];
          wr[u] = __int_as_float(a.y);
          yr[u] = aload(&src[a.x + lane]);
        }
      }
      #pragma unroll
      for (int u = 0; u < 7; u++)
        if (u < rem) s0 = fmaf(wr[u], yr[u], s0);
    }
  }
  return ((s0+s1)+(s2+s3)) + ((s4+s5)+(s6+s7));
}

// ---- fused tail: EXACT R17 structure (262 us, proven). Untouched.
__global__ __launch_bounds__(1024, 4) void tail_loop(
    const float* __restrict__ Xq, const float* __restrict__ Pt,
    const float* __restrict__ pn, const float* __restrict__ qn,
    const int* __restrict__ nbr, const float* __restrict__ dnbr,
    const float* __restrict__ sigma,
    float* d2min, float* denom, float* wh,
    float* rowsum, int* indeg, int* rowptr, int* fillc,
    int* colA, float* wA, float* buf0, float* buf1,
    unsigned long long* pslot,
    int* gcnt, int* gen, int* garr, int* __restrict__ out)
{
  __shared__ int   sdm[2];
  __shared__ float sdelta;
  __shared__ union {
    float pchunk[CHK * N_C];                // 64 KB, P0a staging
    struct {
      int   ipart[1024];
      int   hist[1024];
      float cand[4096];
      int   candn, b1s, b2s;
    } s;
  } U;
  __shared__ int2  adjL[16 * ADJ_CAP];      // 12 KB, per-wave adjacency

  const int tid  = threadIdx.x;
  const int lane = tid & 63;
  const int wv   = tid >> 6;
  const int row  = blockIdx.x * 16 + wv;
  if (tid == 0){ sdm[0] = 0; sdm[1] = 0; }

  // ---------- P0a: a-row via LDS-staged Pt chunks (bit-exact dp order) ----------
  const float* xr = Xq + (size_t)row * DIM;
  const f4*    xr4 = (const f4*)xr;
  float dp[8];
  #pragma unroll
  for (int u = 0; u < 8; u++) dp[u] = 0.f;

  for (int f0 = 0; f0 < DIM; f0 += CHK){
    // cooperative stage: CHK*64 floats = 4096 f4; 1024 threads x 4 f4
    const f4* srcv = (const f4*)(Pt + (size_t)f0 * N_C);
    f4* dstv = (f4*)U.pchunk;
    #pragma unroll
    for (int u = 0; u < 4; u++) dstv[tid + u * 1024] = srcv[tid + u * 1024];
    __syncthreads();
    #pragma unroll 1
    for (int f = 0; f < CHK; f += 8){
      const f4 xa = xr4[(f0 + f) >> 2];
      const f4 xb = xr4[((f0 + f) >> 2) + 1];
      const float* pc = U.pchunk + f * N_C + lane;
      dp[0] = fmaf(xa[0], pc[0      ], dp[0]);
      dp[1] = fmaf(xa[1], pc[N_C    ], dp[1]);
      dp[2] = fmaf(xa[2], pc[N_C * 2], dp[2]);
      dp[3] = fmaf(xa[3], pc[N_C * 3], dp[3]);
      dp[4] = fmaf(xb[0], pc[N_C * 4], dp[4]);
      dp[5] = fmaf(xb[1], pc[N_C * 5], dp[5]);
      dp[6] = fmaf(xb[2], pc[N_C * 6], dp[6]);
      dp[7] = fmaf(xb[3], pc[N_C * 7], dp[7]);
    }
    __syncthreads();                        // before next chunk overwrite
  }
  const float dot = ((dp[0]+dp[1])+(dp[2]+dp[3])) + ((dp[4]+dp[5])+(dp[6]+dp[7]));
  const float av  = fmaxf(qn[row] + pn[lane] - 2.0f * dot, 0.0f);
  const float d2m = wave_min64(av);
  if (lane == 0) astore(&d2min[row], d2m);

  // ---------- P0b: edge weights + degrees ----------
  const int e = blockIdx.x * 1024 + tid;
  if (e < N_Q * KNN){
    const int i = e / KNN;
    const int j = nbr[e];
    float wgt = 0.5f * expf(-dnbr[e] / (sigma[i] * sigma[j]));
    astore(&wh[e], wgt);
    atomicAdd(&rowsum[i], wgt);
    atomicAdd(&rowsum[j], wgt);
    atomicAdd(&indeg[j], 1);
  }

  __syncthreads();
  if (tid == 0) gbar_leader(garr, gcnt, gen, 1);
  __syncthreads();

  // ---------- P1: y0 + scan (block 0) + median (block 1) ----------
  float xv = -av;
  float m = wave_max64(xv), ee = expf(xv - m), ss = wave_sum64(ee);
  float prev = ee / ss;                    // y0
  astore(&buf0[row * N_C + lane], prev);

  if (blockIdx.x == 0){
    int* ipart = U.s.ipart;
    const int base = tid * 4;
    int c0 = aloadi(&indeg[base]),     c1 = aloadi(&indeg[base + 1]);
    int c2 = aloadi(&indeg[base + 2]), c3 = aloadi(&indeg[base + 3]);
    const int s4 = c0 + c1 + c2 + c3;
    ipart[tid] = s4;
    __syncthreads();
    for (int off = 1; off < 1024; off <<= 1){
      int v = (tid >= off) ? ipart[tid - off] : 0;
      __syncthreads();
      ipart[tid] += v;
      __syncthreads();
    }
    int run = ipart[tid] - s4;
    astorei(&rowptr[base    ], KNN * (base    ) + run); run += c0;
    astorei(&rowptr[base + 1], KNN * (base + 1) + run); run += c1;
    astorei(&rowptr[base + 2], KNN * (base + 2) + run); run += c2;
    astorei(&rowptr[base + 3], KNN * (base + 3) + run);
    if (tid == 1023) astorei(&rowptr[N_Q], KNN * N_Q + ipart[1023]);
  }
  if (blockIdx.x == 1){
    int*   hist = U.s.hist;
    float* cand = U.s.cand;
    const int base = tid * 4;
    float dv[4];
    #pragma unroll
    for (int u = 0; u < 4; u++) dv[u] = sqrtf(aload(&d2min[base + u]));
    float mn = fminf(fminf(dv[0], dv[1]), fminf(dv[2], dv[3]));
    float mx = fmaxf(fmaxf(dv[0], dv[1]), fmaxf(dv[2], dv[3]));
    mn = wave_min64(mn); mx = wave_max64(mx);
    if (lane == 0){ cand[wv] = mn; cand[wv + 16] = mx; }
    __syncthreads();
    if (tid == 0){
      float a = cand[0], b = cand[16];
      for (int k = 1; k < 16; k++){ a = fminf(a, cand[k]); b = fmaxf(b, cand[16 + k]); }
      cand[32] = a; cand[33] = b;
    }
    __syncthreads();
    mn = cand[32]; mx = cand[33];
    const float rng = mx - mn;
    const float scale = (rng > 0.f) ? (1024.0f / rng) : 0.f;
    hist[tid] = 0;
    __syncthreads();
    int bidx[4];
    #pragma unroll
    for (int u = 0; u < 4; u++){
      int b = (int)((dv[u] - mn) * scale);
      b = b < 0 ? 0 : (b > 1023 ? 1023 : b);
      bidx[u] = b;
      atomicAdd(&hist[b], 1);
    }
    __syncthreads();
    for (int off = 1; off < 1024; off <<= 1){
      int v = (tid >= off) ? hist[tid - off] : 0;
      __syncthreads();
      hist[tid] += v;
      __syncthreads();
    }
    if (hist[tid] >= 2048 && (tid == 0 || hist[tid - 1] < 2048)) U.s.b1s = tid;
    if (hist[tid] >= 2049 && (tid == 0 || hist[tid - 1] < 2049)) U.s.b2s = tid;
    if (tid == 0) U.s.candn = 0;
    __syncthreads();
    const int b1 = U.s.b1s, b2 = U.s.b2s;
    const int cntBefore = (b1 > 0) ? hist[b1 - 1] : 0;
    #pragma unroll
    for (int u = 0; u < 4; u++){
      if (bidx[u] >= b1 && bidx[u] <= b2){
        int pos = atomicAdd(&U.s.candn, 1);
        cand[pos] = dv[u];
      }
    }
    __syncthreads();
    const int mcnt = U.s.candn;
    int P = 2; while (P < mcnt) P <<= 1;
    for (int i2 = mcnt + tid; i2 < P; i2 += 1024) cand[i2] = FLT_MAX;
    __syncthreads();
    for (int k = 2; k <= P; k <<= 1){
      for (int st = k >> 1; st > 0; st >>= 1){
        for (int i2 = tid; i2 < P; i2 += 1024){
          int j2 = i2 ^ st;
          if (j2 > i2){
            float a2 = cand[i2], b3 = cand[j2];
            bool up = ((i2 & k) == 0);
            if (up ? (a2 > b3) : (a2 < b3)){ cand[i2] = b3; cand[j2] = a2; }
          }
        }
        __syncthreads();
      }
    }
    if (tid == 0){
      float v1 = cand[2047 - cntBefore], v2 = cand[2048 - cntBefore];
      float med = 0.5f * (v1 + v2);
      astore(denom, 2.0f * med * med + 1e-8f);
    }
  }

  __syncthreads();
  if (tid == 0) gbar_leader(garr, gcnt, gen, 2);
  __syncthreads();

  // ---------- P2: CSR fill + per-row coef ----------
  if (e < N_Q * KNN){
    const int i = e / KNN, tt = e % KNN;
    const int j = nbr[e];
    const float wgt = aload(&wh[e]);
    const int p = aloadi(&rowptr[i]) + tt;
    colA[p] = j * N_C; wA[p] = wgt;
    const int q = aloadi(&rowptr[j]) + KNN + atomicAdd(&fillc[j], 1);
    colA[q] = i * N_C; wA[q] = wgt;
  }
  const float cf = expf(-d2m / aload(denom)) / (aload(&rowsum[row]) + 1e-8f);
  const int p0  = aloadi(&rowptr[row]);
  const int p1v = aloadi(&rowptr[row + 1]);

  __builtin_amdgcn_fence(__ATOMIC_RELEASE, "agent");
  __syncthreads();
  if (tid == 0) gbar_leader(garr, gcnt, gen, 3);
  __syncthreads();
  __builtin_amdgcn_fence(__ATOMIC_ACQUIRE, "agent");

  // ---------- preload loop-invariant adjacency into LDS ----------
  {
    const int deg  = p1v - p0;
    const int ncap = deg < ADJ_CAP ? deg : ADJ_CAP;
    for (int u = lane; u < ncap; u += 64)
      adjL[wv * ADJ_CAP + u] = make_int2(colA[p0 + u], __float_as_int(wA[p0 + u]));
  }
  __syncthreads();
  const int2* adj = adjL + wv * ADJ_CAP;

  // ---------- P3: y1 = step(y0); publish delta via pbar phase 1 ----------
  float cur;
  {
    float sum = spmv_row(buf0, adj, colA, wA, p0, p1v, lane);
    float xv2 = -av + cf * sum;
    float mm = wave_max64(xv2), e2 = expf(xv2 - mm), ss2 = wave_sum64(e2);
    cur = e2 / ss2;
    astore(&buf1[row * N_C + lane], cur);
  }
  float dm = wave_max64(fabsf(cur - prev));
  if (lane == 0) atomicMax(&sdm[1], __float_as_int(dm));
  __syncthreads();                         // drains all waves' y stores + LDS
  if (wv == 0) pbar_wave0(pslot, 1, sdm, &sdelta, lane);
  __syncthreads();
  float delta = sdelta;

  // ---------- P4: the while-loop ----------
  int par = 1;                             // buffer currently holding y_new
  for (int t = 0;; t++){
    if (t >= MAX_ITER || delta < EPS_CONV) break;
    const float* src = par ? buf1 : buf0;
    float*       dst = par ? buf0 : buf1;
    float sum = spmv_row(src, adj, colA, wA, p0, p1v, lane);
    float xv2 = -av + cf * sum;
    float mm = wave_max64(xv2), e2 = expf(xv2 - mm), ss2 = wave_sum64(e2);
    float nxt = e2 / ss2;
    astore(&dst[row * N_C + lane], nxt);
    const int ph = t + 2;
    dm = wave_max64(fabsf(nxt - cur));
    if (lane == 0) atomicMax(&sdm[ph & 1], __float_as_int(dm));
    __syncthreads();
    if (wv == 0) pbar_wave0(pslot, ph, sdm, &sdelta, lane);
    __syncthreads();
    delta = sdelta;
    prev = cur; cur = nxt; par ^= 1;
  }

  // argmax of y (prev); first occurrence on ties
  float bv = prev; int bi = lane;
  #pragma unroll
  for (int o = 32; o; o >>= 1){
    float ov = __shfl_xor(bv, o, 64); int oi = __shfl_xor(bi, o, 64);
    if (ov > bv || (ov == bv && oi < bi)){ bv = ov; bi = oi; }
  }
  if (lane == 0) out[row] = bi;
}

extern "C" void kernel_launch(void* const* d_in, const int* in_sizes, int n_in,
                              void* d_out, int out_size, void* d_ws, size_t ws_size,
                              hipStream_t stream)
{
  const float* feat_s = (const float*)d_in[0];
  const int*   y_s    = (const int*)d_in[1];
  const float* feat_q = (const float*)d_in[2];
  int* out = (int*)d_out;

  char* wp = (char*)d_ws;
  auto alloc = [&](size_t bytes) -> char* {
    char* p = wp;
    wp += (bytes + 255) & ~(size_t)255;
    return p;
  };
  float*     Dq  = (float*)alloc((size_t)N_Q * N_Q * 4);     // 64 MB
  _Float16*  Xh  = (_Float16*)alloc((size_t)N_Q * DIM * 2);  // 8 MB
  _Float16*  Xl  = (_Float16*)alloc((size_t)N_Q * DIM * 2);  // 8 MB
  float* Pt     = (float*)alloc((size_t)DIM * N_C * 4);
  float* pn     = (float*)alloc(N_C * 4);
  float* qn     = (float*)alloc(N_Q * 4);
  float* d2min  = (float*)alloc(N_Q * 4);
  float* denom  = (float*)alloc(256);
  int*   nbr    = (int*)alloc((size_t)N_Q * KNN * 4);
  float* dnbr   = (float*)alloc((size_t)N_Q * KNN * 4);
  float* sigma  = (float*)alloc(N_Q * 4);
  float* wh     = (float*)alloc((size_t)N_Q * KNN * 4);
  int*   rowptr = (int*)alloc((N_Q + 1) * 4);
  int*   colA   = (int*)alloc((size_t)2 * N_Q * KNN * 4);
  float* wA     = (float*)alloc((size_t)2 * N_Q * KNN * 4);
  float* buf0   = (float*)alloc((size_t)N_Q * N_C * 4);
  float* buf1   = (float*)alloc((size_t)N_Q * N_C * 4);
  // zero-region: rowsum | indeg | fillc | syncw | garr | pslot (packed, 4KB)
  const size_t zbytes = (size_t)N_Q*12 + 256 + 2048 + 2 * NBLK * 8;
  char*  zbase  = alloc(zbytes);
  float* rowsum = (float*)(zbase);
  int*   indeg  = (int*)(zbase + N_Q*4);
  int*   fillc  = (int*)(zbase + N_Q*8);
  int*   syncw  = (int*)(zbase + N_Q*12);
  int*   garr   = (int*)(zbase + N_Q*12 + 256);
  unsigned long long* pslot = (unsigned long long*)(zbase + N_Q*12 + 256 + 2048);

  hipMemsetAsync(zbase, 0, zbytes, stream);

  setup_kernel <<<N_Q + N_C, 256, 0, stream>>>(feat_s, y_s, Pt, pn, feat_q, qn, Xh, Xl);
  dist_mfma    <<<512, 256, 0, stream>>>(Xh, Xl, qn, Dq);
  topk_kernel  <<<N_Q, 256, 0, stream>>>(Dq, nbr, dnbr, sigma);

  int* gcnt = &syncw[0];
  int* gen  = &syncw[32];
  const float* Xq = feat_q;
  void* args[] = {&Xq, &Pt, &pn, &qn, &nbr, &dnbr, &sigma,
                  &d2min, &denom, &wh, &rowsum, &indeg, &rowptr, &fillc,
                  &colA, &wA, &buf0, &buf1, &pslot,
                  &gcnt, &gen, &garr, &out};
  hipLaunchCooperativeKernel((void*)tail_loop, dim3(NBLK), dim3(1024), args, 0, stream);
}